// Round 7
// baseline (209.784 us; speedup 1.0000x reference)
//
#include <hip/hip_runtime.h>
#include <hip/hip_bf16.h>

#define N_NODES 8192
#define F_IN    512
#define H_DIM   256
#define O_DIM   128
#define C_DIM   64
#define E_EDGES 262144

typedef __attribute__((ext_vector_type(8))) short bf16x8;
typedef __attribute__((ext_vector_type(8))) _Float16 f16x8;
typedef __attribute__((ext_vector_type(4))) float f32x4;

__device__ inline unsigned short f2bf(float v) {
    __hip_bfloat16 h = __float2bfloat16(v);
    return *reinterpret_cast<unsigned short*>(&h);
}
__device__ inline float bf2f(unsigned short u) {
    return __uint_as_float((unsigned)u << 16);
}
__device__ inline void split2(float v, unsigned short& hi, unsigned short& lo) {
    hi = f2bf(v);
    lo = f2bf(v - bf2f(hi));
}
__device__ inline float4 bf4_to_f4(ushort4 u) {
    float4 f;
    f.x = bf2f(u.x); f.y = bf2f(u.y); f.z = bf2f(u.z); f.w = bf2f(u.w);
    return f;
}

// ---------------- fused split (+ cnt zeroing): x -> xh/xl ; W1,W2 -> transposed hi/lo ----------------
__global__ __launch_bounds__(256) void split_all_kernel(
    const float* __restrict__ x, unsigned short* __restrict__ xh, unsigned short* __restrict__ xl,
    const float* __restrict__ W1, unsigned short* __restrict__ w1th, unsigned short* __restrict__ w1tl,
    const float* __restrict__ W2, unsigned short* __restrict__ w2th, unsigned short* __restrict__ w2tl,
    int* __restrict__ cnt)
{
    const int NX4 = N_NODES * F_IN / 4;
    const int NW1 = F_IN * H_DIM;
    const int NW2 = H_DIM * O_DIM;
    int idx = blockIdx.x * 256 + threadIdx.x;
    if (idx < N_NODES) cnt[idx] = 0;
    if (idx < NX4) {
        float4 v = ((const float4*)x)[idx];
        ushort4 h, l;
        split2(v.x, h.x, l.x);
        split2(v.y, h.y, l.y);
        split2(v.z, h.z, l.z);
        split2(v.w, h.w, l.w);
        ((ushort4*)xh)[idx] = h;
        ((ushort4*)xl)[idx] = l;
    } else if (idx < NX4 + NW1) {
        int j = idx - NX4;
        int k = j / H_DIM, n = j % H_DIM;
        unsigned short h, l;
        split2(W1[j], h, l);
        w1th[n * F_IN + k] = h;
        w1tl[n * F_IN + k] = l;
    } else if (idx < NX4 + NW1 + NW2) {
        int j = idx - NX4 - NW1;
        int k = j / O_DIM, n = j % O_DIM;
        unsigned short h, l;
        split2(W2[j], h, l);
        w2th[n * H_DIM + k] = h;
        w2tl[n * H_DIM + k] = l;
    }
}

// ---------------- CSR build ----------------
__global__ __launch_bounds__(256) void hist_kernel(const int* __restrict__ dst,
                                                   int* __restrict__ cnt) {
    int e = blockIdx.x * 256 + threadIdx.x;
    if (e < E_EDGES) atomicAdd(&cnt[dst[e]], 1);
}

__global__ __launch_bounds__(1024) void scan_kernel(const int* __restrict__ cnt,
                                                    int* __restrict__ row_ptr,
                                                    int* __restrict__ cursor,
                                                    float* __restrict__ dinv) {
    __shared__ int wsum[16];
    const int t = threadIdx.x;
    const int lane = t & 63;
    const int wv = t >> 6;
    const int base = t * 8;
    int c[8];
    int s = 0;
#pragma unroll
    for (int j = 0; j < 8; ++j) { c[j] = cnt[base + j]; s += c[j]; }
    int ssc = s;
#pragma unroll
    for (int d = 1; d < 64; d <<= 1) {
        int v = __shfl_up(ssc, d, 64);
        if (lane >= d) ssc += v;
    }
    if (lane == 63) wsum[wv] = ssc;
    __syncthreads();
    if (t < 16) {
        int v = wsum[t];
        int sc = v;
#pragma unroll
        for (int d = 1; d < 16; d <<= 1) {
            int u = __shfl_up(sc, d, 64);
            if (t >= d) sc += u;
        }
        wsum[t] = sc - v;
    }
    __syncthreads();
    int ex = wsum[wv] + (ssc - s);
#pragma unroll
    for (int j = 0; j < 8; ++j) {
        row_ptr[base + j] = ex;
        cursor[base + j] = ex;
        ex += c[j];
        dinv[base + j] = rsqrtf((float)c[j] + 1.0f);
    }
    if (t == 1023) row_ptr[N_NODES] = ex;
}

__global__ __launch_bounds__(256) void fill_kernel(const int* __restrict__ srcv,
                                                   const int* __restrict__ dstv,
                                                   int* __restrict__ cursor,
                                                   int* __restrict__ csr_src) {
    int e = blockIdx.x * 256 + threadIdx.x;
    if (e < E_EDGES) {
        int d = dstv[e];
        int pos = atomicAdd(&cursor[d], 1);
        csr_src[pos] = srcv[e];
    }
}

// ---------------- split-bf16 MFMA GEMM with register double-buffered K-loop ----------------
#define LOADF(S, koff)                                                          \
    do {                                                                        \
        const int kof_ = (koff) + kg * 8;                                       \
        _Pragma("unroll")                                                       \
        for (int mi = 0; mi < MW; ++mi) {                                       \
            size_t off = (size_t)(m0 + mi * 16 + r) * K + kof_;                 \
            ah##S[mi] = *(const bf16x8*)(Ah + off);                             \
            al##S[mi] = *(const bf16x8*)(Al + off);                             \
        }                                                                       \
        _Pragma("unroll")                                                       \
        for (int ni = 0; ni < NW; ++ni) {                                       \
            size_t off = (size_t)(n0 + ni * 16 + r) * K + kof_;                 \
            bh##S[ni] = *(const bf16x8*)(Bth + off);                            \
            bl##S[ni] = *(const bf16x8*)(Btl + off);                            \
        }                                                                       \
    } while (0)

#define MFMAF(S)                                                                                        \
    do {                                                                                                \
        _Pragma("unroll")                                                                               \
        for (int mi = 0; mi < MW; ++mi)                                                                 \
            _Pragma("unroll")                                                                           \
            for (int ni = 0; ni < NW; ++ni) {                                                           \
                acc[mi][ni] = __builtin_amdgcn_mfma_f32_16x16x32_bf16(ah##S[mi], bh##S[ni], acc[mi][ni], 0, 0, 0); \
                acc[mi][ni] = __builtin_amdgcn_mfma_f32_16x16x32_bf16(ah##S[mi], bl##S[ni], acc[mi][ni], 0, 0, 0); \
                acc[mi][ni] = __builtin_amdgcn_mfma_f32_16x16x32_bf16(al##S[mi], bh##S[ni], acc[mi][ni], 0, 0, 0); \
            }                                                                                           \
    } while (0)

template<int N, int K, int MW, int NW>
__global__ __launch_bounds__(256) void gemm_mfma_kernel(
    const unsigned short* __restrict__ Ah, const unsigned short* __restrict__ Al,
    const unsigned short* __restrict__ Bth, const unsigned short* __restrict__ Btl,
    const float* __restrict__ dinv, unsigned short* __restrict__ out)
{
    const int tid = threadIdx.x;
    const int lane = tid & 63;
    const int wid = tid >> 6;
    const int r = lane & 15;
    const int kg = lane >> 4;
    const int m0 = blockIdx.y * (2 * MW * 16) + (wid >> 1) * (MW * 16);
    const int n0 = blockIdx.x * (2 * NW * 16) + (wid & 1) * (NW * 16);

    f32x4 acc[MW][NW];
#pragma unroll
    for (int mi = 0; mi < MW; ++mi)
#pragma unroll
        for (int ni = 0; ni < NW; ++ni) acc[mi][ni] = (f32x4){0.f, 0.f, 0.f, 0.f};

    bf16x8 ahA[MW], alA[MW], bhA[NW], blA[NW];
    bf16x8 ahB[MW], alB[MW], bhB[NW], blB[NW];

    LOADF(A, 0);
    for (int k0 = 0; k0 < K; k0 += 64) {
        LOADF(B, k0 + 32);
        MFMAF(A);
        if (k0 + 64 < K) LOADF(A, k0 + 64);
        MFMAF(B);
    }

#pragma unroll
    for (int mi = 0; mi < MW; ++mi) {
        int rowb = m0 + mi * 16 + kg * 4;
        float di[4];
#pragma unroll
        for (int i = 0; i < 4; ++i) di[i] = dinv[rowb + i];
#pragma unroll
        for (int ni = 0; ni < NW; ++ni) {
            int col = n0 + ni * 16 + r;
#pragma unroll
            for (int i = 0; i < 4; ++i)
                out[(size_t)(rowb + i) * N + col] = f2bf(di[i] * acc[mi][ni][i]);
        }
    }
}

// ---------------- gather layer 1 (bf16 g1): 8-deep ILP ----------------
__global__ __launch_bounds__(256) void gather1_kernel(
    const unsigned short* __restrict__ g,
    const int* __restrict__ row_ptr, const int* __restrict__ csr_src,
    const float* __restrict__ dinv, const float* __restrict__ b,
    unsigned short* __restrict__ hh, unsigned short* __restrict__ hl)
{
    const int wid = threadIdx.x >> 6;
    const int lane = threadIdx.x & 63;
    const int node = blockIdx.x * 4 + wid;
    if (node >= N_NODES) return;

    const ushort4* G4 = (const ushort4*)g;
    const int beg = row_ptr[node];
    const int end = row_ptr[node + 1];

    float4 acc = bf4_to_f4(G4[(size_t)node * 64 + lane]);
    float4 acc2 = make_float4(0.f, 0.f, 0.f, 0.f);

    int e = beg;
    for (; e + 8 <= end; e += 8) {
        ushort4 u[8];
#pragma unroll
        for (int j = 0; j < 8; ++j) u[j] = G4[(size_t)csr_src[e + j] * 64 + lane];
#pragma unroll
        for (int j = 0; j < 8; j += 2) {
            float4 v0 = bf4_to_f4(u[j]);
            float4 v1 = bf4_to_f4(u[j + 1]);
            acc.x += v0.x; acc.y += v0.y; acc.z += v0.z; acc.w += v0.w;
            acc2.x += v1.x; acc2.y += v1.y; acc2.z += v1.z; acc2.w += v1.w;
        }
    }
    for (; e < end; ++e) {
        float4 v0 = bf4_to_f4(G4[(size_t)csr_src[e] * 64 + lane]);
        acc.x += v0.x; acc.y += v0.y; acc.z += v0.z; acc.w += v0.w;
    }
    acc.x += acc2.x; acc.y += acc2.y; acc.z += acc2.z; acc.w += acc2.w;

    float di = dinv[node];
    const float4 bv = ((const float4*)b)[lane];
    float4 rr;
    rr.x = di * acc.x + bv.x;
    rr.y = di * acc.y + bv.y;
    rr.z = di * acc.z + bv.z;
    rr.w = di * acc.w + bv.w;
    rr.x = rr.x > 0.f ? rr.x : 0.f;
    rr.y = rr.y > 0.f ? rr.y : 0.f;
    rr.z = rr.z > 0.f ? rr.z : 0.f;
    rr.w = rr.w > 0.f ? rr.w : 0.f;

    ushort4 h, l;
    split2(rr.x, h.x, l.x);
    split2(rr.y, h.y, l.y);
    split2(rr.z, h.z, l.z);
    split2(rr.w, h.w, l.w);
    ((ushort4*)hh)[(size_t)node * 64 + lane] = h;
    ((ushort4*)hl)[(size_t)node * 64 + lane] = l;
}

// ---------------- fused gather layer 2 + head: z -> mu, logvar, zr (fp16) ----------------
__global__ __launch_bounds__(128) void gather_head_kernel(
    const unsigned short* __restrict__ g2,
    const int* __restrict__ row_ptr, const int* __restrict__ csr_src,
    const float* __restrict__ dinv, const float* __restrict__ b2,
    const float* __restrict__ Wmu, const float* __restrict__ bmu,
    const float* __restrict__ Wlv, const float* __restrict__ blv,
    const float* __restrict__ eps,
    float* __restrict__ mu_out, float* __restrict__ lv_out,
    _Float16* __restrict__ zr)
{
    __shared__ float zs[O_DIM];
    __shared__ float mu_s[C_DIM];
    __shared__ float lv_s[C_DIM];
    const int node = blockIdx.x;
    const int t = threadIdx.x;

    const int beg = row_ptr[node];
    const int end = row_ptr[node + 1];

    float acc = bf2f(g2[(size_t)node * O_DIM + t]);
    float acc2 = 0.f;
    int e = beg;
    for (; e + 8 <= end; e += 8) {
        unsigned short u[8];
#pragma unroll
        for (int j = 0; j < 8; ++j) u[j] = g2[(size_t)csr_src[e + j] * O_DIM + t];
#pragma unroll
        for (int j = 0; j < 8; j += 2) {
            acc += bf2f(u[j]);
            acc2 += bf2f(u[j + 1]);
        }
    }
    for (; e < end; ++e) acc += bf2f(g2[(size_t)csr_src[e] * O_DIM + t]);
    acc += acc2;

    zs[t] = dinv[node] * acc + b2[t];
    __syncthreads();

    const int c = t & 63;
    const float* W = (t < 64) ? Wmu : Wlv;
    float s = 0.f;
#pragma unroll 8
    for (int k = 0; k < O_DIM; ++k) s += zs[k] * W[k * C_DIM + c];
    if (t < 64) {
        s += bmu[c];
        mu_out[(size_t)node * C_DIM + c] = s;
        mu_s[c] = s;
    } else {
        s += blv[c];
        lv_out[(size_t)node * C_DIM + c] = s;
        lv_s[c] = s;
    }
    __syncthreads();
    if (t < 64) {
        float stdv = __expf(0.5f * lv_s[c]);
        float v = mu_s[c] + eps[(size_t)node * C_DIM + c] * stdv;
        zr[(size_t)node * C_DIM + c] = (_Float16)v;
    }
}

// ---------------- adj = sigmoid(zr @ zr^T) via fp16 MFMA, nontemporal stores ----------------
__global__ __launch_bounds__(256) void adj_mfma_kernel(
    const _Float16* __restrict__ Z, float* __restrict__ out)
{
    const int tid = threadIdx.x;
    const int lane = tid & 63;
    const int wid = tid >> 6;
    const int r = lane & 15;
    const int kg = lane >> 4;
    const int m0 = blockIdx.y * 128 + (wid >> 1) * 64;
    const int n0 = blockIdx.x * 128 + (wid & 1) * 64;

    f16x8 a[4][2], b[4][2];
#pragma unroll
    for (int mi = 0; mi < 4; ++mi)
#pragma unroll
        for (int ks = 0; ks < 2; ++ks) {
            a[mi][ks] = *(const f16x8*)(Z + (size_t)(m0 + mi * 16 + r) * C_DIM + ks * 32 + kg * 8);
            b[mi][ks] = *(const f16x8*)(Z + (size_t)(n0 + mi * 16 + r) * C_DIM + ks * 32 + kg * 8);
        }

    f32x4 acc[4][4];
#pragma unroll
    for (int mi = 0; mi < 4; ++mi)
#pragma unroll
        for (int ni = 0; ni < 4; ++ni) acc[mi][ni] = (f32x4){0.f, 0.f, 0.f, 0.f};

#pragma unroll
    for (int mi = 0; mi < 4; ++mi)
#pragma unroll
        for (int ni = 0; ni < 4; ++ni) {
            acc[mi][ni] = __builtin_amdgcn_mfma_f32_16x16x32_f16(a[mi][0], b[ni][0], acc[mi][ni], 0, 0, 0);
            acc[mi][ni] = __builtin_amdgcn_mfma_f32_16x16x32_f16(a[mi][1], b[ni][1], acc[mi][ni], 0, 0, 0);
        }

#pragma unroll
    for (int mi = 0; mi < 4; ++mi) {
        int rowb = m0 + mi * 16 + kg * 4;
#pragma unroll
        for (int ni = 0; ni < 4; ++ni) {
            int col = n0 + ni * 16 + r;
#pragma unroll
            for (int i = 0; i < 4; ++i) {
                float v = acc[mi][ni][i];
                float e = __expf(-v);
                float sg = __builtin_amdgcn_rcpf(1.0f + e);
                __builtin_nontemporal_store(sg, &out[(size_t)(rowb + i) * N_NODES + col]);
            }
        }
    }
}

extern "C" void kernel_launch(void* const* d_in, const int* in_sizes, int n_in,
                              void* d_out, int out_size, void* d_ws, size_t ws_size,
                              hipStream_t stream) {
    const float* x   = (const float*)d_in[0];
    const int*   ei  = (const int*)  d_in[1];
    const float* eps = (const float*)d_in[2];
    const float* W1  = (const float*)d_in[3];
    const float* b1  = (const float*)d_in[4];
    const float* W2  = (const float*)d_in[5];
    const float* b2  = (const float*)d_in[6];
    const float* Wmu = (const float*)d_in[7];
    const float* bmu = (const float*)d_in[8];
    const float* Wlv = (const float*)d_in[9];
    const float* blv = (const float*)d_in[10];
    float* out = (float*)d_out;

    const int* srcv = ei;
    const int* dstv = ei + E_EDGES;

    char* p = (char*)d_ws;
    auto carve = [&](size_t bytes) -> void* {
        void* q = (void*)p;
        p += (bytes + 255) & ~(size_t)255;
        return q;
    };
    int* cnt      = (int*)carve(N_NODES * 4);
    int* row_ptr  = (int*)carve((N_NODES + 1) * 4);
    int* cursor   = (int*)carve(N_NODES * 4);
    int* csr_src  = (int*)carve(E_EDGES * 4);
    float* dinv   = (float*)carve(N_NODES * 4);
    unsigned short* xh   = (unsigned short*)carve((size_t)N_NODES * F_IN * 2);
    unsigned short* xl   = (unsigned short*)carve((size_t)N_NODES * F_IN * 2);
    unsigned short* w1th = (unsigned short*)carve((size_t)F_IN * H_DIM * 2);
    unsigned short* w1tl = (unsigned short*)carve((size_t)F_IN * H_DIM * 2);
    unsigned short* w2th = (unsigned short*)carve((size_t)H_DIM * O_DIM * 2);
    unsigned short* w2tl = (unsigned short*)carve((size_t)H_DIM * O_DIM * 2);
    unsigned short* g1b  = (unsigned short*)carve((size_t)N_NODES * H_DIM * 2);
    unsigned short* hh   = (unsigned short*)carve((size_t)N_NODES * H_DIM * 2);
    unsigned short* hl   = (unsigned short*)carve((size_t)N_NODES * H_DIM * 2);
    unsigned short* g2b  = (unsigned short*)carve((size_t)N_NODES * O_DIM * 2);
    _Float16* zr         = (_Float16*)carve((size_t)N_NODES * C_DIM * 2);

    float* mu_out = out + (size_t)N_NODES * N_NODES;
    float* lv_out = mu_out + (size_t)N_NODES * C_DIM;

    // ---- 1. fused splits (+ cnt zero) ----
    {
        const int total = N_NODES * F_IN / 4 + F_IN * H_DIM + H_DIM * O_DIM;
        split_all_kernel<<<(total + 255) / 256, 256, 0, stream>>>(
            x, xh, xl, W1, w1th, w1tl, W2, w2th, w2tl, cnt);
    }

    // ---- 2-4. CSR build + dinv ----
    hist_kernel<<<E_EDGES / 256, 256, 0, stream>>>(dstv, cnt);
    scan_kernel<<<1, 1024, 0, stream>>>(cnt, row_ptr, cursor, dinv);
    fill_kernel<<<E_EDGES / 256, 256, 0, stream>>>(srcv, dstv, cursor, csr_src);

    // ---- 5. layer 1 GEMM ----
    {
        dim3 grid(H_DIM / 64, N_NODES / 64);   // MW=2, NW=2
        gemm_mfma_kernel<H_DIM, F_IN, 2, 2><<<grid, 256, 0, stream>>>(
            xh, xl, w1th, w1tl, dinv, g1b);
    }

    // ---- 6. gather 1 -> h (bf16 hi/lo) ----
    gather1_kernel<<<N_NODES / 4, 256, 0, stream>>>(g1b, row_ptr, csr_src, dinv, b1, hh, hl);

    // ---- 7. layer 2 GEMM ----
    {
        dim3 grid(O_DIM / 64, N_NODES / 32);   // MW=1, NW=2
        gemm_mfma_kernel<O_DIM, H_DIM, 1, 2><<<grid, 256, 0, stream>>>(
            hh, hl, w2th, w2tl, dinv, g2b);
    }

    // ---- 8. fused gather 2 + head (zr fp16) ----
    gather_head_kernel<<<N_NODES, 128, 0, stream>>>(
        g2b, row_ptr, csr_src, dinv, b2, Wmu, bmu, Wlv, blv, eps,
        mu_out, lv_out, zr);

    // ---- 9. adjacency reconstruction (fp16 MFMA) ----
    {
        dim3 grid(N_NODES / 128, N_NODES / 128);
        adj_mfma_kernel<<<grid, 256, 0, stream>>>(zr, out);
    }
}

// Round 8
// 187.955 us; speedup vs baseline: 1.1161x; 1.1161x over previous
//
#include <hip/hip_runtime.h>
#include <hip/hip_bf16.h>

#define N_NODES 8192
#define F_IN    512
#define H_DIM   256
#define O_DIM   128
#define C_DIM   64
#define E_EDGES 262144
#define BCAP    96

typedef __attribute__((ext_vector_type(8))) short bf16x8;
typedef __attribute__((ext_vector_type(8))) _Float16 f16x8;
typedef __attribute__((ext_vector_type(4))) float f32x4;

__device__ inline unsigned short f2bf(float v) {
    __hip_bfloat16 h = __float2bfloat16(v);
    return *reinterpret_cast<unsigned short*>(&h);
}
__device__ inline float bf2f(unsigned short u) {
    return __uint_as_float((unsigned)u << 16);
}
__device__ inline void split2(float v, unsigned short& hi, unsigned short& lo) {
    hi = f2bf(v);
    lo = f2bf(v - bf2f(hi));
}
__device__ inline float4 bf4_to_f4(ushort4 u) {
    float4 f;
    f.x = bf2f(u.x); f.y = bf2f(u.y); f.z = bf2f(u.z); f.w = bf2f(u.w);
    return f;
}

// ---------------- K1: fused split (x, W1^T, W2^T -> bf16 hi/lo) + bucket CSR fill ----------------
// cnt must be zeroed (memset) before this kernel.
__global__ __launch_bounds__(256) void split_fill_kernel(
    const float* __restrict__ x, unsigned short* __restrict__ xh, unsigned short* __restrict__ xl,
    const float* __restrict__ W1, unsigned short* __restrict__ w1th, unsigned short* __restrict__ w1tl,
    const float* __restrict__ W2, unsigned short* __restrict__ w2th, unsigned short* __restrict__ w2tl,
    const int* __restrict__ srcv, const int* __restrict__ dstv,
    int* __restrict__ cnt, int* __restrict__ slots)
{
    const int NX4 = N_NODES * F_IN / 4;       // 1048576
    const int NW1 = F_IN * H_DIM;             // 131072
    const int NW2 = H_DIM * O_DIM;            // 32768
    const int S   = NX4 + NW1 + NW2;          // 1212416
    int idx = blockIdx.x * 256 + threadIdx.x;
    if (idx < NX4) {
        float4 v = ((const float4*)x)[idx];
        ushort4 h, l;
        split2(v.x, h.x, l.x);
        split2(v.y, h.y, l.y);
        split2(v.z, h.z, l.z);
        split2(v.w, h.w, l.w);
        ((ushort4*)xh)[idx] = h;
        ((ushort4*)xl)[idx] = l;
    } else if (idx < NX4 + NW1) {
        int j = idx - NX4;
        int k = j / H_DIM, n = j % H_DIM;
        unsigned short h, l;
        split2(W1[j], h, l);
        w1th[n * F_IN + k] = h;
        w1tl[n * F_IN + k] = l;
    } else if (idx < S) {
        int j = idx - NX4 - NW1;
        int k = j / O_DIM, n = j % O_DIM;
        unsigned short h, l;
        split2(W2[j], h, l);
        w2th[n * H_DIM + k] = h;
        w2tl[n * H_DIM + k] = l;
    } else if (idx < S + E_EDGES) {
        int e = idx - S;
        int d = dstv[e];
        int pos = atomicAdd(&cnt[d], 1);
        slots[d * BCAP + pos] = srcv[e];
    }
}

// ---------------- split-bf16 MFMA GEMM with register double-buffered K-loop ----------------
// out = bf16(dinv ⊙ (A @ Bt^T)); dinv = rsqrt(cnt+1) computed on the fly.
#define LOADF(S, koff)                                                          \
    do {                                                                        \
        const int kof_ = (koff) + kg * 8;                                       \
        _Pragma("unroll")                                                       \
        for (int mi = 0; mi < MW; ++mi) {                                       \
            size_t off = (size_t)(m0 + mi * 16 + r) * K + kof_;                 \
            ah##S[mi] = *(const bf16x8*)(Ah + off);                             \
            al##S[mi] = *(const bf16x8*)(Al + off);                             \
        }                                                                       \
        _Pragma("unroll")                                                       \
        for (int ni = 0; ni < NW; ++ni) {                                       \
            size_t off = (size_t)(n0 + ni * 16 + r) * K + kof_;                 \
            bh##S[ni] = *(const bf16x8*)(Bth + off);                            \
            bl##S[ni] = *(const bf16x8*)(Btl + off);                            \
        }                                                                       \
    } while (0)

#define MFMAF(S)                                                                                        \
    do {                                                                                                \
        _Pragma("unroll")                                                                               \
        for (int mi = 0; mi < MW; ++mi)                                                                 \
            _Pragma("unroll")                                                                           \
            for (int ni = 0; ni < NW; ++ni) {                                                           \
                acc[mi][ni] = __builtin_amdgcn_mfma_f32_16x16x32_bf16(ah##S[mi], bh##S[ni], acc[mi][ni], 0, 0, 0); \
                acc[mi][ni] = __builtin_amdgcn_mfma_f32_16x16x32_bf16(ah##S[mi], bl##S[ni], acc[mi][ni], 0, 0, 0); \
                acc[mi][ni] = __builtin_amdgcn_mfma_f32_16x16x32_bf16(al##S[mi], bh##S[ni], acc[mi][ni], 0, 0, 0); \
            }                                                                                           \
    } while (0)

template<int N, int K, int MW, int NW>
__global__ __launch_bounds__(256) void gemm_mfma_kernel(
    const unsigned short* __restrict__ Ah, const unsigned short* __restrict__ Al,
    const unsigned short* __restrict__ Bth, const unsigned short* __restrict__ Btl,
    const int* __restrict__ cnt, unsigned short* __restrict__ out)
{
    const int tid = threadIdx.x;
    const int lane = tid & 63;
    const int wid = tid >> 6;
    const int r = lane & 15;
    const int kg = lane >> 4;
    const int m0 = blockIdx.y * (2 * MW * 16) + (wid >> 1) * (MW * 16);
    const int n0 = blockIdx.x * (2 * NW * 16) + (wid & 1) * (NW * 16);

    f32x4 acc[MW][NW];
#pragma unroll
    for (int mi = 0; mi < MW; ++mi)
#pragma unroll
        for (int ni = 0; ni < NW; ++ni) acc[mi][ni] = (f32x4){0.f, 0.f, 0.f, 0.f};

    bf16x8 ahA[MW], alA[MW], bhA[NW], blA[NW];
    bf16x8 ahB[MW], alB[MW], bhB[NW], blB[NW];

    LOADF(A, 0);
    for (int k0 = 0; k0 < K; k0 += 64) {
        LOADF(B, k0 + 32);
        MFMAF(A);
        if (k0 + 64 < K) LOADF(A, k0 + 64);
        MFMAF(B);
    }

#pragma unroll
    for (int mi = 0; mi < MW; ++mi) {
        int rowb = m0 + mi * 16 + kg * 4;
        float di[4];
#pragma unroll
        for (int i = 0; i < 4; ++i) di[i] = rsqrtf((float)cnt[rowb + i] + 1.0f);
#pragma unroll
        for (int ni = 0; ni < NW; ++ni) {
            int col = n0 + ni * 16 + r;
#pragma unroll
            for (int i = 0; i < 4; ++i)
                out[(size_t)(rowb + i) * N + col] = f2bf(di[i] * acc[mi][ni][i]);
        }
    }
}

// ---------------- gather layer 1 (bucket CSR): h = relu(dinv*(sum+self)+b), hi/lo out ----------------
__global__ __launch_bounds__(256) void gather1_kernel(
    const unsigned short* __restrict__ g,
    const int* __restrict__ cnt, const int* __restrict__ slots,
    const float* __restrict__ b,
    unsigned short* __restrict__ hh, unsigned short* __restrict__ hl)
{
    const int wid = threadIdx.x >> 6;
    const int lane = threadIdx.x & 63;
    const int node = blockIdx.x * 4 + wid;
    if (node >= N_NODES) return;

    const ushort4* G4 = (const ushort4*)g;
    const int deg = cnt[node];
    const int* sl = slots + node * BCAP;

    float4 acc = bf4_to_f4(G4[(size_t)node * 64 + lane]);
    float4 acc2 = make_float4(0.f, 0.f, 0.f, 0.f);

    int e = 0;
    for (; e + 8 <= deg; e += 8) {
        ushort4 u[8];
#pragma unroll
        for (int j = 0; j < 8; ++j) u[j] = G4[(size_t)sl[e + j] * 64 + lane];
#pragma unroll
        for (int j = 0; j < 8; j += 2) {
            float4 v0 = bf4_to_f4(u[j]);
            float4 v1 = bf4_to_f4(u[j + 1]);
            acc.x += v0.x; acc.y += v0.y; acc.z += v0.z; acc.w += v0.w;
            acc2.x += v1.x; acc2.y += v1.y; acc2.z += v1.z; acc2.w += v1.w;
        }
    }
    for (; e < deg; ++e) {
        float4 v0 = bf4_to_f4(G4[(size_t)sl[e] * 64 + lane]);
        acc.x += v0.x; acc.y += v0.y; acc.z += v0.z; acc.w += v0.w;
    }
    acc.x += acc2.x; acc.y += acc2.y; acc.z += acc2.z; acc.w += acc2.w;

    float di = rsqrtf((float)deg + 1.0f);
    const float4 bv = ((const float4*)b)[lane];
    float4 rr;
    rr.x = di * acc.x + bv.x;
    rr.y = di * acc.y + bv.y;
    rr.z = di * acc.z + bv.z;
    rr.w = di * acc.w + bv.w;
    rr.x = rr.x > 0.f ? rr.x : 0.f;
    rr.y = rr.y > 0.f ? rr.y : 0.f;
    rr.z = rr.z > 0.f ? rr.z : 0.f;
    rr.w = rr.w > 0.f ? rr.w : 0.f;

    ushort4 h, l;
    split2(rr.x, h.x, l.x);
    split2(rr.y, h.y, l.y);
    split2(rr.z, h.z, l.z);
    split2(rr.w, h.w, l.w);
    ((ushort4*)hh)[(size_t)node * 64 + lane] = h;
    ((ushort4*)hl)[(size_t)node * 64 + lane] = l;
}

// ---------------- fused gather layer 2 + head (bucket CSR): z -> mu, logvar, zr (fp16) ----------------
__global__ __launch_bounds__(128) void gather_head_kernel(
    const unsigned short* __restrict__ g2,
    const int* __restrict__ cnt, const int* __restrict__ slots,
    const float* __restrict__ b2,
    const float* __restrict__ Wmu, const float* __restrict__ bmu,
    const float* __restrict__ Wlv, const float* __restrict__ blv,
    const float* __restrict__ eps,
    float* __restrict__ mu_out, float* __restrict__ lv_out,
    _Float16* __restrict__ zr)
{
    __shared__ float zs[O_DIM];
    __shared__ float mu_s[C_DIM];
    __shared__ float lv_s[C_DIM];
    const int node = blockIdx.x;
    const int t = threadIdx.x;

    const int deg = cnt[node];
    const int* sl = slots + node * BCAP;

    float acc = bf2f(g2[(size_t)node * O_DIM + t]);
    float acc2 = 0.f;
    int e = 0;
    for (; e + 8 <= deg; e += 8) {
        unsigned short u[8];
#pragma unroll
        for (int j = 0; j < 8; ++j) u[j] = g2[(size_t)sl[e + j] * O_DIM + t];
#pragma unroll
        for (int j = 0; j < 8; j += 2) {
            acc += bf2f(u[j]);
            acc2 += bf2f(u[j + 1]);
        }
    }
    for (; e < deg; ++e) acc += bf2f(g2[(size_t)sl[e] * O_DIM + t]);
    acc += acc2;

    zs[t] = rsqrtf((float)deg + 1.0f) * acc + b2[t];
    __syncthreads();

    const int c = t & 63;
    const float* W = (t < 64) ? Wmu : Wlv;
    float s = 0.f;
#pragma unroll 8
    for (int k = 0; k < O_DIM; ++k) s += zs[k] * W[k * C_DIM + c];
    if (t < 64) {
        s += bmu[c];
        mu_out[(size_t)node * C_DIM + c] = s;
        mu_s[c] = s;
    } else {
        s += blv[c];
        lv_out[(size_t)node * C_DIM + c] = s;
        lv_s[c] = s;
    }
    __syncthreads();
    if (t < 64) {
        float stdv = __expf(0.5f * lv_s[c]);
        float v = mu_s[c] + eps[(size_t)node * C_DIM + c] * stdv;
        zr[(size_t)node * C_DIM + c] = (_Float16)v;
    }
}

// ---------------- adj = sigmoid(zr @ zr^T) via fp16 MFMA, nontemporal stores ----------------
__global__ __launch_bounds__(256) void adj_mfma_kernel(
    const _Float16* __restrict__ Z, float* __restrict__ out)
{
    const int tid = threadIdx.x;
    const int lane = tid & 63;
    const int wid = tid >> 6;
    const int r = lane & 15;
    const int kg = lane >> 4;
    const int m0 = blockIdx.y * 128 + (wid >> 1) * 64;
    const int n0 = blockIdx.x * 128 + (wid & 1) * 64;

    f16x8 a[4][2], b[4][2];
#pragma unroll
    for (int mi = 0; mi < 4; ++mi)
#pragma unroll
        for (int ks = 0; ks < 2; ++ks) {
            a[mi][ks] = *(const f16x8*)(Z + (size_t)(m0 + mi * 16 + r) * C_DIM + ks * 32 + kg * 8);
            b[mi][ks] = *(const f16x8*)(Z + (size_t)(n0 + mi * 16 + r) * C_DIM + ks * 32 + kg * 8);
        }

    f32x4 acc[4][4];
#pragma unroll
    for (int mi = 0; mi < 4; ++mi)
#pragma unroll
        for (int ni = 0; ni < 4; ++ni) acc[mi][ni] = (f32x4){0.f, 0.f, 0.f, 0.f};

#pragma unroll
    for (int mi = 0; mi < 4; ++mi)
#pragma unroll
        for (int ni = 0; ni < 4; ++ni) {
            acc[mi][ni] = __builtin_amdgcn_mfma_f32_16x16x32_f16(a[mi][0], b[ni][0], acc[mi][ni], 0, 0, 0);
            acc[mi][ni] = __builtin_amdgcn_mfma_f32_16x16x32_f16(a[mi][1], b[ni][1], acc[mi][ni], 0, 0, 0);
        }

#pragma unroll
    for (int mi = 0; mi < 4; ++mi) {
        int rowb = m0 + mi * 16 + kg * 4;
#pragma unroll
        for (int ni = 0; ni < 4; ++ni) {
            int col = n0 + ni * 16 + r;
#pragma unroll
            for (int i = 0; i < 4; ++i) {
                float v = acc[mi][ni][i];
                float e = __expf(-v);
                float sg = __builtin_amdgcn_rcpf(1.0f + e);
                __builtin_nontemporal_store(sg, &out[(size_t)(rowb + i) * N_NODES + col]);
            }
        }
    }
}

extern "C" void kernel_launch(void* const* d_in, const int* in_sizes, int n_in,
                              void* d_out, int out_size, void* d_ws, size_t ws_size,
                              hipStream_t stream) {
    const float* x   = (const float*)d_in[0];
    const int*   ei  = (const int*)  d_in[1];
    const float* eps = (const float*)d_in[2];
    const float* W1  = (const float*)d_in[3];
    const float* b1  = (const float*)d_in[4];
    const float* W2  = (const float*)d_in[5];
    const float* b2  = (const float*)d_in[6];
    const float* Wmu = (const float*)d_in[7];
    const float* bmu = (const float*)d_in[8];
    const float* Wlv = (const float*)d_in[9];
    const float* blv = (const float*)d_in[10];
    float* out = (float*)d_out;

    const int* srcv = ei;
    const int* dstv = ei + E_EDGES;

    char* p = (char*)d_ws;
    auto carve = [&](size_t bytes) -> void* {
        void* q = (void*)p;
        p += (bytes + 255) & ~(size_t)255;
        return q;
    };
    int* cnt      = (int*)carve(N_NODES * 4);
    int* slots    = (int*)carve((size_t)N_NODES * BCAP * 4);
    unsigned short* xh   = (unsigned short*)carve((size_t)N_NODES * F_IN * 2);
    unsigned short* xl   = (unsigned short*)carve((size_t)N_NODES * F_IN * 2);
    unsigned short* w1th = (unsigned short*)carve((size_t)F_IN * H_DIM * 2);
    unsigned short* w1tl = (unsigned short*)carve((size_t)F_IN * H_DIM * 2);
    unsigned short* w2th = (unsigned short*)carve((size_t)H_DIM * O_DIM * 2);
    unsigned short* w2tl = (unsigned short*)carve((size_t)H_DIM * O_DIM * 2);
    unsigned short* g1b  = (unsigned short*)carve((size_t)N_NODES * H_DIM * 2);
    unsigned short* hh   = (unsigned short*)carve((size_t)N_NODES * H_DIM * 2);
    unsigned short* hl   = (unsigned short*)carve((size_t)N_NODES * H_DIM * 2);
    unsigned short* g2b  = (unsigned short*)carve((size_t)N_NODES * O_DIM * 2);
    _Float16* zr         = (_Float16*)carve((size_t)N_NODES * C_DIM * 2);

    float* mu_out = out + (size_t)N_NODES * N_NODES;
    float* lv_out = mu_out + (size_t)N_NODES * C_DIM;

    // ---- 0. zero bucket counters (memset node) ----
    hipMemsetAsync(cnt, 0, N_NODES * 4, stream);

    // ---- 1. fused splits + bucket CSR fill ----
    {
        const int total = N_NODES * F_IN / 4 + F_IN * H_DIM + H_DIM * O_DIM + E_EDGES;
        split_fill_kernel<<<(total + 255) / 256, 256, 0, stream>>>(
            x, xh, xl, W1, w1th, w1tl, W2, w2th, w2tl, srcv, dstv, cnt, slots);
    }

    // ---- 2. layer 1 GEMM ----
    {
        dim3 grid(H_DIM / 64, N_NODES / 64);   // MW=2, NW=2
        gemm_mfma_kernel<H_DIM, F_IN, 2, 2><<<grid, 256, 0, stream>>>(
            xh, xl, w1th, w1tl, cnt, g1b);
    }

    // ---- 3. gather 1 -> h (bf16 hi/lo) ----
    gather1_kernel<<<N_NODES / 4, 256, 0, stream>>>(g1b, cnt, slots, b1, hh, hl);

    // ---- 4. layer 2 GEMM ----
    {
        dim3 grid(O_DIM / 64, N_NODES / 32);   // MW=1, NW=2
        gemm_mfma_kernel<O_DIM, H_DIM, 1, 2><<<grid, 256, 0, stream>>>(
            hh, hl, w2th, w2tl, cnt, g2b);
    }

    // ---- 5. fused gather 2 + head (zr fp16) ----
    gather_head_kernel<<<N_NODES, 128, 0, stream>>>(
        g2b, cnt, slots, b2, Wmu, bmu, Wlv, blv, eps,
        mu_out, lv_out, zr);

    // ---- 6. adjacency reconstruction (fp16 MFMA) ----
    {
        dim3 grid(N_NODES / 128, N_NODES / 128);
        adj_mfma_kernel<<<grid, 256, 0, stream>>>(zr, out);
    }
}

// Round 9
// 183.742 us; speedup vs baseline: 1.1417x; 1.0229x over previous
//
#include <hip/hip_runtime.h>
#include <hip/hip_bf16.h>

#define N_NODES 8192
#define F_IN    512
#define H_DIM   256
#define O_DIM   128
#define C_DIM   64
#define E_EDGES 262144
#define BCAP    96

typedef __attribute__((ext_vector_type(8))) short bf16x8;
typedef __attribute__((ext_vector_type(8))) _Float16 f16x8;
typedef __attribute__((ext_vector_type(4))) float f32x4;

__device__ inline unsigned short f2bf(float v) {
    __hip_bfloat16 h = __float2bfloat16(v);
    return *reinterpret_cast<unsigned short*>(&h);
}
__device__ inline float bf2f(unsigned short u) {
    return __uint_as_float((unsigned)u << 16);
}
__device__ inline void split2(float v, unsigned short& hi, unsigned short& lo) {
    hi = f2bf(v);
    lo = f2bf(v - bf2f(hi));
}
__device__ inline float4 bf4_to_f4(ushort4 u) {
    float4 f;
    f.x = bf2f(u.x); f.y = bf2f(u.y); f.z = bf2f(u.z); f.w = bf2f(u.w);
    return f;
}
__device__ inline bf16x8 pack_bf8(float4 a, float4 b) {
    bf16x8 r;
    r[0] = (short)f2bf(a.x); r[1] = (short)f2bf(a.y);
    r[2] = (short)f2bf(a.z); r[3] = (short)f2bf(a.w);
    r[4] = (short)f2bf(b.x); r[5] = (short)f2bf(b.y);
    r[6] = (short)f2bf(b.z); r[7] = (short)f2bf(b.w);
    return r;
}

// ---------------- K1: prep — zero cnt, split W1^T and W2^T to bf16 hi/lo ----------------
__global__ __launch_bounds__(256) void prep_kernel(
    const float* __restrict__ W1, unsigned short* __restrict__ w1th, unsigned short* __restrict__ w1tl,
    const float* __restrict__ W2, unsigned short* __restrict__ w2th, unsigned short* __restrict__ w2tl,
    int* __restrict__ cnt)
{
    const int NW1 = F_IN * H_DIM;             // 131072
    const int NW2 = H_DIM * O_DIM;            // 32768
    int idx = blockIdx.x * 256 + threadIdx.x;
    if (idx < N_NODES) cnt[idx] = 0;
    if (idx < NW1) {
        int k = idx / H_DIM, n = idx % H_DIM;
        unsigned short h, l;
        split2(W1[idx], h, l);
        w1th[n * F_IN + k] = h;
        w1tl[n * F_IN + k] = l;
    } else if (idx < NW1 + NW2) {
        int j = idx - NW1;
        int k = j / O_DIM, n = j % O_DIM;
        unsigned short h, l;
        split2(W2[j], h, l);
        w2th[n * H_DIM + k] = h;
        w2tl[n * H_DIM + k] = l;
    }
}

// ---------------- K2: gemm1 — edge bucket-fill + raw1 = bf16(bf16(x) @ (W1h+W1l)) ----------------
// x read fp32 directly, converted in-register. No dinv (cnt is being filled concurrently).
__global__ __launch_bounds__(256) void gemm1_kernel(
    const float* __restrict__ x,
    const unsigned short* __restrict__ Bth, const unsigned short* __restrict__ Btl,
    const int* __restrict__ srcv, const int* __restrict__ dstv,
    int* __restrict__ cnt, int* __restrict__ slots,
    unsigned short* __restrict__ out)   // raw1 [N_NODES][H_DIM]
{
    // edge fill: exactly 2 edges per thread (512 blocks * 256 thr * 2 = 262144)
    {
        int flat = (blockIdx.y * gridDim.x + blockIdx.x) * 256 + threadIdx.x;
        int e0 = flat * 2;
        int d0 = dstv[e0];
        int p0 = atomicAdd(&cnt[d0], 1);
        slots[d0 * BCAP + p0] = srcv[e0];
        int d1 = dstv[e0 + 1];
        int p1 = atomicAdd(&cnt[d1], 1);
        slots[d1 * BCAP + p1] = srcv[e0 + 1];
    }

    constexpr int N = H_DIM, K = F_IN, MW = 2, NW = 2;
    const int tid = threadIdx.x;
    const int lane = tid & 63;
    const int wid = tid >> 6;
    const int r = lane & 15;
    const int kg = lane >> 4;
    const int m0 = blockIdx.y * (2 * MW * 16) + (wid >> 1) * (MW * 16);
    const int n0 = blockIdx.x * (2 * NW * 16) + (wid & 1) * (NW * 16);

    f32x4 acc[MW][NW];
#pragma unroll
    for (int mi = 0; mi < MW; ++mi)
#pragma unroll
        for (int ni = 0; ni < NW; ++ni) acc[mi][ni] = (f32x4){0.f, 0.f, 0.f, 0.f};

    for (int k0 = 0; k0 < K; k0 += 32) {
        const int kof = k0 + kg * 8;
        bf16x8 a[MW], bh[NW], bl[NW];
#pragma unroll
        for (int mi = 0; mi < MW; ++mi) {
            const float* xr = x + (size_t)(m0 + mi * 16 + r) * K + kof;
            float4 f0 = *(const float4*)xr;
            float4 f1 = *(const float4*)(xr + 4);
            a[mi] = pack_bf8(f0, f1);
        }
#pragma unroll
        for (int ni = 0; ni < NW; ++ni) {
            size_t off = (size_t)(n0 + ni * 16 + r) * K + kof;
            bh[ni] = *(const bf16x8*)(Bth + off);
            bl[ni] = *(const bf16x8*)(Btl + off);
        }
#pragma unroll
        for (int mi = 0; mi < MW; ++mi)
#pragma unroll
            for (int ni = 0; ni < NW; ++ni) {
                acc[mi][ni] = __builtin_amdgcn_mfma_f32_16x16x32_bf16(a[mi], bh[ni], acc[mi][ni], 0, 0, 0);
                acc[mi][ni] = __builtin_amdgcn_mfma_f32_16x16x32_bf16(a[mi], bl[ni], acc[mi][ni], 0, 0, 0);
            }
    }

#pragma unroll
    for (int mi = 0; mi < MW; ++mi) {
        int rowb = m0 + mi * 16 + kg * 4;
#pragma unroll
        for (int ni = 0; ni < NW; ++ni) {
            int col = n0 + ni * 16 + r;
#pragma unroll
            for (int i = 0; i < 4; ++i)
                out[(size_t)(rowb + i) * N + col] = f2bf(acc[mi][ni][i]);
        }
    }
}

// ---------------- generic split-bf16 MFMA GEMM (for layer 2): out = bf16(dinv ⊙ (A@Bt^T)) ----------------
#define LOADF(S, koff)                                                          \
    do {                                                                        \
        const int kof_ = (koff) + kg * 8;                                       \
        _Pragma("unroll")                                                       \
        for (int mi = 0; mi < MW; ++mi) {                                       \
            size_t off = (size_t)(m0 + mi * 16 + r) * K + kof_;                 \
            ah##S[mi] = *(const bf16x8*)(Ah + off);                             \
            al##S[mi] = *(const bf16x8*)(Al + off);                             \
        }                                                                       \
        _Pragma("unroll")                                                       \
        for (int ni = 0; ni < NW; ++ni) {                                       \
            size_t off = (size_t)(n0 + ni * 16 + r) * K + kof_;                 \
            bh##S[ni] = *(const bf16x8*)(Bth + off);                            \
            bl##S[ni] = *(const bf16x8*)(Btl + off);                            \
        }                                                                       \
    } while (0)

#define MFMAF(S)                                                                                        \
    do {                                                                                                \
        _Pragma("unroll")                                                                               \
        for (int mi = 0; mi < MW; ++mi)                                                                 \
            _Pragma("unroll")                                                                           \
            for (int ni = 0; ni < NW; ++ni) {                                                           \
                acc[mi][ni] = __builtin_amdgcn_mfma_f32_16x16x32_bf16(ah##S[mi], bh##S[ni], acc[mi][ni], 0, 0, 0); \
                acc[mi][ni] = __builtin_amdgcn_mfma_f32_16x16x32_bf16(ah##S[mi], bl##S[ni], acc[mi][ni], 0, 0, 0); \
                acc[mi][ni] = __builtin_amdgcn_mfma_f32_16x16x32_bf16(al##S[mi], bh##S[ni], acc[mi][ni], 0, 0, 0); \
            }                                                                                           \
    } while (0)

template<int N, int K, int MW, int NW>
__global__ __launch_bounds__(256) void gemm_mfma_kernel(
    const unsigned short* __restrict__ Ah, const unsigned short* __restrict__ Al,
    const unsigned short* __restrict__ Bth, const unsigned short* __restrict__ Btl,
    const int* __restrict__ cnt, unsigned short* __restrict__ out)
{
    const int tid = threadIdx.x;
    const int lane = tid & 63;
    const int wid = tid >> 6;
    const int r = lane & 15;
    const int kg = lane >> 4;
    const int m0 = blockIdx.y * (2 * MW * 16) + (wid >> 1) * (MW * 16);
    const int n0 = blockIdx.x * (2 * NW * 16) + (wid & 1) * (NW * 16);

    f32x4 acc[MW][NW];
#pragma unroll
    for (int mi = 0; mi < MW; ++mi)
#pragma unroll
        for (int ni = 0; ni < NW; ++ni) acc[mi][ni] = (f32x4){0.f, 0.f, 0.f, 0.f};

    bf16x8 ahA[MW], alA[MW], bhA[NW], blA[NW];
    bf16x8 ahB[MW], alB[MW], bhB[NW], blB[NW];

    LOADF(A, 0);
    for (int k0 = 0; k0 < K; k0 += 64) {
        LOADF(B, k0 + 32);
        MFMAF(A);
        if (k0 + 64 < K) LOADF(A, k0 + 64);
        MFMAF(B);
    }

#pragma unroll
    for (int mi = 0; mi < MW; ++mi) {
        int rowb = m0 + mi * 16 + kg * 4;
        float di[4];
#pragma unroll
        for (int i = 0; i < 4; ++i) di[i] = rsqrtf((float)cnt[rowb + i] + 1.0f);
#pragma unroll
        for (int ni = 0; ni < NW; ++ni) {
            int col = n0 + ni * 16 + r;
#pragma unroll
            for (int i = 0; i < 4; ++i)
                out[(size_t)(rowb + i) * N + col] = f2bf(di[i] * acc[mi][ni][i]);
        }
    }
}

// ---------------- K3: gather1 — h = relu(di*(Σ dj*raw_j) + di²*raw_i + b), hi/lo out ----------------
__global__ __launch_bounds__(256) void gather1_kernel(
    const unsigned short* __restrict__ raw,   // [N_NODES][256] bf16, unscaled
    const int* __restrict__ cnt, const int* __restrict__ slots,
    const float* __restrict__ b,
    unsigned short* __restrict__ hh, unsigned short* __restrict__ hl)
{
    const int wid = threadIdx.x >> 6;
    const int lane = threadIdx.x & 63;
    const int node = blockIdx.x * 4 + wid;
    if (node >= N_NODES) return;

    const ushort4* G4 = (const ushort4*)raw;
    const int deg = cnt[node];
    const int* sl = slots + node * BCAP;
    const float di = rsqrtf((float)deg + 1.0f);

    float4 selfv = bf4_to_f4(G4[(size_t)node * 64 + lane]);
    float4 acc, acc2;
    acc.x = di * selfv.x; acc.y = di * selfv.y;
    acc.z = di * selfv.z; acc.w = di * selfv.w;
    acc2 = make_float4(0.f, 0.f, 0.f, 0.f);

    int e = 0;
    for (; e + 8 <= deg; e += 8) {
        int s[8];
        ushort4 u[8];
        float d[8];
#pragma unroll
        for (int j = 0; j < 8; ++j) s[j] = sl[e + j];
#pragma unroll
        for (int j = 0; j < 8; ++j) u[j] = G4[(size_t)s[j] * 64 + lane];
#pragma unroll
        for (int j = 0; j < 8; ++j) d[j] = rsqrtf((float)cnt[s[j]] + 1.0f);
#pragma unroll
        for (int j = 0; j < 8; j += 2) {
            float4 v0 = bf4_to_f4(u[j]);
            float4 v1 = bf4_to_f4(u[j + 1]);
            acc.x = fmaf(d[j], v0.x, acc.x);   acc.y = fmaf(d[j], v0.y, acc.y);
            acc.z = fmaf(d[j], v0.z, acc.z);   acc.w = fmaf(d[j], v0.w, acc.w);
            acc2.x = fmaf(d[j+1], v1.x, acc2.x); acc2.y = fmaf(d[j+1], v1.y, acc2.y);
            acc2.z = fmaf(d[j+1], v1.z, acc2.z); acc2.w = fmaf(d[j+1], v1.w, acc2.w);
        }
    }
    for (; e < deg; ++e) {
        int s0 = sl[e];
        float d0 = rsqrtf((float)cnt[s0] + 1.0f);
        float4 v0 = bf4_to_f4(G4[(size_t)s0 * 64 + lane]);
        acc.x = fmaf(d0, v0.x, acc.x); acc.y = fmaf(d0, v0.y, acc.y);
        acc.z = fmaf(d0, v0.z, acc.z); acc.w = fmaf(d0, v0.w, acc.w);
    }
    acc.x += acc2.x; acc.y += acc2.y; acc.z += acc2.z; acc.w += acc2.w;

    const float4 bv = ((const float4*)b)[lane];
    float4 rr;
    rr.x = di * acc.x + bv.x;
    rr.y = di * acc.y + bv.y;
    rr.z = di * acc.z + bv.z;
    rr.w = di * acc.w + bv.w;
    rr.x = rr.x > 0.f ? rr.x : 0.f;
    rr.y = rr.y > 0.f ? rr.y : 0.f;
    rr.z = rr.z > 0.f ? rr.z : 0.f;
    rr.w = rr.w > 0.f ? rr.w : 0.f;

    ushort4 h, l;
    split2(rr.x, h.x, l.x);
    split2(rr.y, h.y, l.y);
    split2(rr.z, h.z, l.z);
    split2(rr.w, h.w, l.w);
    ((ushort4*)hh)[(size_t)node * 64 + lane] = h;
    ((ushort4*)hl)[(size_t)node * 64 + lane] = l;
}

// ---------------- K5: fused gather layer 2 + head: z -> mu, logvar, zr (fp16) ----------------
__global__ __launch_bounds__(128) void gather_head_kernel(
    const unsigned short* __restrict__ g2,   // [N_NODES][128] bf16, dinv-scaled
    const int* __restrict__ cnt, const int* __restrict__ slots,
    const float* __restrict__ b2,
    const float* __restrict__ Wmu, const float* __restrict__ bmu,
    const float* __restrict__ Wlv, const float* __restrict__ blv,
    const float* __restrict__ eps,
    float* __restrict__ mu_out, float* __restrict__ lv_out,
    _Float16* __restrict__ zr)
{
    __shared__ float zs[O_DIM];
    __shared__ float mu_s[C_DIM];
    __shared__ float lv_s[C_DIM];
    const int node = blockIdx.x;
    const int t = threadIdx.x;

    const int deg = cnt[node];
    const int* sl = slots + node * BCAP;

    float acc = bf2f(g2[(size_t)node * O_DIM + t]);
    float acc2 = 0.f;
    int e = 0;
    for (; e + 8 <= deg; e += 8) {
        unsigned short u[8];
#pragma unroll
        for (int j = 0; j < 8; ++j) u[j] = g2[(size_t)sl[e + j] * O_DIM + t];
#pragma unroll
        for (int j = 0; j < 8; j += 2) {
            acc += bf2f(u[j]);
            acc2 += bf2f(u[j + 1]);
        }
    }
    for (; e < deg; ++e) acc += bf2f(g2[(size_t)sl[e] * O_DIM + t]);
    acc += acc2;

    zs[t] = rsqrtf((float)deg + 1.0f) * acc + b2[t];
    __syncthreads();

    const int c = t & 63;
    const float* W = (t < 64) ? Wmu : Wlv;
    float s = 0.f;
#pragma unroll 8
    for (int k = 0; k < O_DIM; ++k) s += zs[k] * W[k * C_DIM + c];
    if (t < 64) {
        s += bmu[c];
        mu_out[(size_t)node * C_DIM + c] = s;
        mu_s[c] = s;
    } else {
        s += blv[c];
        lv_out[(size_t)node * C_DIM + c] = s;
        lv_s[c] = s;
    }
    __syncthreads();
    if (t < 64) {
        float stdv = __expf(0.5f * lv_s[c]);
        float v = mu_s[c] + eps[(size_t)node * C_DIM + c] * stdv;
        zr[(size_t)node * C_DIM + c] = (_Float16)v;
    }
}

// ---------------- K6: adj = sigmoid(zr @ zr^T) via fp16 MFMA, nontemporal stores ----------------
__global__ __launch_bounds__(256) void adj_mfma_kernel(
    const _Float16* __restrict__ Z, float* __restrict__ out)
{
    const int tid = threadIdx.x;
    const int lane = tid & 63;
    const int wid = tid >> 6;
    const int r = lane & 15;
    const int kg = lane >> 4;
    const int m0 = blockIdx.y * 128 + (wid >> 1) * 64;
    const int n0 = blockIdx.x * 128 + (wid & 1) * 64;

    f16x8 a[4][2], b[4][2];
#pragma unroll
    for (int mi = 0; mi < 4; ++mi)
#pragma unroll
        for (int ks = 0; ks < 2; ++ks) {
            a[mi][ks] = *(const f16x8*)(Z + (size_t)(m0 + mi * 16 + r) * C_DIM + ks * 32 + kg * 8);
            b[mi][ks] = *(const f16x8*)(Z + (size_t)(n0 + mi * 16 + r) * C_DIM + ks * 32 + kg * 8);
        }

    f32x4 acc[4][4];
#pragma unroll
    for (int mi = 0; mi < 4; ++mi)
#pragma unroll
        for (int ni = 0; ni < 4; ++ni) acc[mi][ni] = (f32x4){0.f, 0.f, 0.f, 0.f};

#pragma unroll
    for (int mi = 0; mi < 4; ++mi)
#pragma unroll
        for (int ni = 0; ni < 4; ++ni) {
            acc[mi][ni] = __builtin_amdgcn_mfma_f32_16x16x32_f16(a[mi][0], b[ni][0], acc[mi][ni], 0, 0, 0);
            acc[mi][ni] = __builtin_amdgcn_mfma_f32_16x16x32_f16(a[mi][1], b[ni][1], acc[mi][ni], 0, 0, 0);
        }

#pragma unroll
    for (int mi = 0; mi < 4; ++mi) {
        int rowb = m0 + mi * 16 + kg * 4;
#pragma unroll
        for (int ni = 0; ni < 4; ++ni) {
            int col = n0 + ni * 16 + r;
#pragma unroll
            for (int i = 0; i < 4; ++i) {
                float v = acc[mi][ni][i];
                float e = __expf(-v);
                float sg = __builtin_amdgcn_rcpf(1.0f + e);
                __builtin_nontemporal_store(sg, &out[(size_t)(rowb + i) * N_NODES + col]);
            }
        }
    }
}

extern "C" void kernel_launch(void* const* d_in, const int* in_sizes, int n_in,
                              void* d_out, int out_size, void* d_ws, size_t ws_size,
                              hipStream_t stream) {
    const float* x   = (const float*)d_in[0];
    const int*   ei  = (const int*)  d_in[1];
    const float* eps = (const float*)d_in[2];
    const float* W1  = (const float*)d_in[3];
    const float* b1  = (const float*)d_in[4];
    const float* W2  = (const float*)d_in[5];
    const float* b2  = (const float*)d_in[6];
    const float* Wmu = (const float*)d_in[7];
    const float* bmu = (const float*)d_in[8];
    const float* Wlv = (const float*)d_in[9];
    const float* blv = (const float*)d_in[10];
    float* out = (float*)d_out;

    const int* srcv = ei;
    const int* dstv = ei + E_EDGES;

    char* p = (char*)d_ws;
    auto carve = [&](size_t bytes) -> void* {
        void* q = (void*)p;
        p += (bytes + 255) & ~(size_t)255;
        return q;
    };
    int* cnt      = (int*)carve(N_NODES * 4);
    int* slots    = (int*)carve((size_t)N_NODES * BCAP * 4);
    unsigned short* w1th = (unsigned short*)carve((size_t)F_IN * H_DIM * 2);
    unsigned short* w1tl = (unsigned short*)carve((size_t)F_IN * H_DIM * 2);
    unsigned short* w2th = (unsigned short*)carve((size_t)H_DIM * O_DIM * 2);
    unsigned short* w2tl = (unsigned short*)carve((size_t)H_DIM * O_DIM * 2);
    unsigned short* raw1 = (unsigned short*)carve((size_t)N_NODES * H_DIM * 2);
    unsigned short* hh   = (unsigned short*)carve((size_t)N_NODES * H_DIM * 2);
    unsigned short* hl   = (unsigned short*)carve((size_t)N_NODES * H_DIM * 2);
    unsigned short* g2b  = (unsigned short*)carve((size_t)N_NODES * O_DIM * 2);
    _Float16* zr         = (_Float16*)carve((size_t)N_NODES * C_DIM * 2);

    float* mu_out = out + (size_t)N_NODES * N_NODES;
    float* lv_out = mu_out + (size_t)N_NODES * C_DIM;

    // ---- 1. prep: cnt zero + weight transposed splits ----
    {
        const int total = F_IN * H_DIM + H_DIM * O_DIM;  // 163840 (>= N_NODES)
        prep_kernel<<<(total + 255) / 256, 256, 0, stream>>>(
            W1, w1th, w1tl, W2, w2th, w2tl, cnt);
    }

    // ---- 2. gemm1: edge bucket-fill + raw1 = bf16(x)@W1(hi/lo) ----
    {
        dim3 grid(H_DIM / 64, N_NODES / 64);   // 4 x 128 = 512 blocks
        gemm1_kernel<<<grid, 256, 0, stream>>>(
            x, w1th, w1tl, srcv, dstv, cnt, slots, raw1);
    }

    // ---- 3. gather1 -> h (bf16 hi/lo), applies both dinv scalings ----
    gather1_kernel<<<N_NODES / 4, 256, 0, stream>>>(raw1, cnt, slots, b1, hh, hl);

    // ---- 4. layer 2 GEMM: g2b = bf16(dinv*(h@W2)) ----
    {
        dim3 grid(O_DIM / 64, N_NODES / 32);   // MW=1, NW=2
        gemm_mfma_kernel<O_DIM, H_DIM, 1, 2><<<grid, 256, 0, stream>>>(
            hh, hl, w2th, w2tl, cnt, g2b);
    }

    // ---- 5. fused gather 2 + head (zr fp16) ----
    gather_head_kernel<<<N_NODES, 128, 0, stream>>>(
        g2b, cnt, slots, b2, Wmu, bmu, Wlv, blv, eps,
        mu_out, lv_out, zr);

    // ---- 6. adjacency reconstruction (fp16 MFMA) ----
    {
        dim3 grid(N_NODES / 128, N_NODES / 128);
        adj_mfma_kernel<<<grid, 256, 0, stream>>>(zr, out);
    }
}

// Round 10
// 179.751 us; speedup vs baseline: 1.1671x; 1.0222x over previous
//
#include <hip/hip_runtime.h>
#include <hip/hip_bf16.h>

#define N_NODES 8192
#define F_IN    512
#define H_DIM   256
#define O_DIM   128
#define C_DIM   64
#define E_EDGES 262144
#define BCAP    96

typedef __attribute__((ext_vector_type(8))) short bf16x8;
typedef __attribute__((ext_vector_type(8))) _Float16 f16x8;
typedef __attribute__((ext_vector_type(4))) float f32x4;

__device__ inline unsigned short f2bf(float v) {
    __hip_bfloat16 h = __float2bfloat16(v);
    return *reinterpret_cast<unsigned short*>(&h);
}
__device__ inline float bf2f(unsigned short u) {
    return __uint_as_float((unsigned)u << 16);
}
__device__ inline void split2(float v, unsigned short& hi, unsigned short& lo) {
    hi = f2bf(v);
    lo = f2bf(v - bf2f(hi));
}
__device__ inline float4 bf4_to_f4(ushort4 u) {
    float4 f;
    f.x = bf2f(u.x); f.y = bf2f(u.y); f.z = bf2f(u.z); f.w = bf2f(u.w);
    return f;
}
__device__ inline bf16x8 pack_bf8(float4 a, float4 b) {
    bf16x8 r;
    r[0] = (short)f2bf(a.x); r[1] = (short)f2bf(a.y);
    r[2] = (short)f2bf(a.z); r[3] = (short)f2bf(a.w);
    r[4] = (short)f2bf(b.x); r[5] = (short)f2bf(b.y);
    r[6] = (short)f2bf(b.z); r[7] = (short)f2bf(b.w);
    return r;
}

// ---------------- K1: prep — zero cnt, split W1^T and W2^T to bf16 hi/lo ----------------
__global__ __launch_bounds__(256) void prep_kernel(
    const float* __restrict__ W1, unsigned short* __restrict__ w1th, unsigned short* __restrict__ w1tl,
    const float* __restrict__ W2, unsigned short* __restrict__ w2th, unsigned short* __restrict__ w2tl,
    int* __restrict__ cnt)
{
    const int NW1 = F_IN * H_DIM;             // 131072
    const int NW2 = H_DIM * O_DIM;            // 32768
    int idx = blockIdx.x * 256 + threadIdx.x;
    if (idx < N_NODES) cnt[idx] = 0;
    if (idx < NW1) {
        int k = idx / H_DIM, n = idx % H_DIM;
        unsigned short h, l;
        split2(W1[idx], h, l);
        w1th[n * F_IN + k] = h;
        w1tl[n * F_IN + k] = l;
    } else if (idx < NW1 + NW2) {
        int j = idx - NW1;
        int k = j / O_DIM, n = j % O_DIM;
        unsigned short h, l;
        split2(W2[j], h, l);
        w2th[n * H_DIM + k] = h;
        w2tl[n * H_DIM + k] = l;
    }
}

// ---------------- K2: gemm1 — edge bucket-fill + raw1 = bf16(bf16(x) @ (W1h+W1l)) ----------------
// Block tile 64x128 (waves 2x2, wave tile 32x64). grid (2, 128) = 256 blocks.
__global__ __launch_bounds__(256) void gemm1_kernel(
    const float* __restrict__ x,
    const unsigned short* __restrict__ Bth, const unsigned short* __restrict__ Btl,
    const int* __restrict__ srcv, const int* __restrict__ dstv,
    int* __restrict__ cnt, int* __restrict__ slots,
    unsigned short* __restrict__ out)   // raw1 [N_NODES][H_DIM]
{
    // edge fill: exactly 4 edges per thread (256 blocks * 256 thr * 4 = 262144)
    {
        int flat = (blockIdx.y * gridDim.x + blockIdx.x) * 256 + threadIdx.x;
        int e0 = flat * 4;
#pragma unroll
        for (int j = 0; j < 4; ++j) {
            int d = dstv[e0 + j];
            int pos = atomicAdd(&cnt[d], 1);
            slots[d * BCAP + pos] = srcv[e0 + j];
        }
    }

    constexpr int N = H_DIM, K = F_IN, MW = 2, NW = 4;
    const int tid = threadIdx.x;
    const int lane = tid & 63;
    const int wid = tid >> 6;
    const int r = lane & 15;
    const int kg = lane >> 4;
    const int m0 = blockIdx.y * (2 * MW * 16) + (wid >> 1) * (MW * 16);
    const int n0 = blockIdx.x * (2 * NW * 16) + (wid & 1) * (NW * 16);

    f32x4 acc[MW][NW];
#pragma unroll
    for (int mi = 0; mi < MW; ++mi)
#pragma unroll
        for (int ni = 0; ni < NW; ++ni) acc[mi][ni] = (f32x4){0.f, 0.f, 0.f, 0.f};

    for (int k0 = 0; k0 < K; k0 += 32) {
        const int kof = k0 + kg * 8;
        bf16x8 a[MW], bh[NW], bl[NW];
#pragma unroll
        for (int mi = 0; mi < MW; ++mi) {
            const float* xr = x + (size_t)(m0 + mi * 16 + r) * K + kof;
            float4 f0 = *(const float4*)xr;
            float4 f1 = *(const float4*)(xr + 4);
            a[mi] = pack_bf8(f0, f1);
        }
#pragma unroll
        for (int ni = 0; ni < NW; ++ni) {
            size_t off = (size_t)(n0 + ni * 16 + r) * K + kof;
            bh[ni] = *(const bf16x8*)(Bth + off);
            bl[ni] = *(const bf16x8*)(Btl + off);
        }
#pragma unroll
        for (int mi = 0; mi < MW; ++mi)
#pragma unroll
            for (int ni = 0; ni < NW; ++ni) {
                acc[mi][ni] = __builtin_amdgcn_mfma_f32_16x16x32_bf16(a[mi], bh[ni], acc[mi][ni], 0, 0, 0);
                acc[mi][ni] = __builtin_amdgcn_mfma_f32_16x16x32_bf16(a[mi], bl[ni], acc[mi][ni], 0, 0, 0);
            }
    }

#pragma unroll
    for (int mi = 0; mi < MW; ++mi) {
        int rowb = m0 + mi * 16 + kg * 4;
#pragma unroll
        for (int ni = 0; ni < NW; ++ni) {
            int col = n0 + ni * 16 + r;
#pragma unroll
            for (int i = 0; i < 4; ++i)
                out[(size_t)(rowb + i) * N + col] = f2bf(acc[mi][ni][i]);
        }
    }
}

// ---------------- K3: fused gather1 + gemm2 ----------------
// 512 blocks x 16 nodes. Phase 1: gather h rows (relu GCN) into XOR-swizzled LDS (bf16).
// Phase 2: g2b[16x128] = bf16(dinv * (h[16x256] @ W2)), A from LDS, B(hi/lo) from global.
__global__ __launch_bounds__(256) void gather_gemm2_kernel(
    const unsigned short* __restrict__ raw,   // raw1 [8192][256] bf16, unscaled
    const int* __restrict__ cnt, const int* __restrict__ slots,
    const float* __restrict__ b1,
    const unsigned short* __restrict__ w2th, const unsigned short* __restrict__ w2tl,
    unsigned short* __restrict__ g2b)         // [8192][128] bf16, dinv-scaled
{
    __shared__ unsigned short hs[16 * 256];   // 8 KB, row stride 512 B, XOR-swizzled slots
    const int tid = threadIdx.x;
    const int wid = tid >> 6;
    const int lane = tid & 63;
    const int nb = blockIdx.x * 16;
    const ushort4* G4 = (const ushort4*)raw;

    // ---- phase 1: each wave gathers 4 node rows ----
    for (int q = 0; q < 4; ++q) {
        const int ln = wid * 4 + q;
        const int node = nb + ln;
        const int deg = cnt[node];
        const int* sl = slots + node * BCAP;
        const float di = rsqrtf((float)deg + 1.0f);

        float4 selfv = bf4_to_f4(G4[(size_t)node * 64 + lane]);
        float4 acc, acc2;
        acc.x = di * selfv.x; acc.y = di * selfv.y;
        acc.z = di * selfv.z; acc.w = di * selfv.w;
        acc2 = make_float4(0.f, 0.f, 0.f, 0.f);

        int e = 0;
        for (; e + 8 <= deg; e += 8) {
            int s[8];
            ushort4 u[8];
            float d[8];
#pragma unroll
            for (int j = 0; j < 8; ++j) s[j] = sl[e + j];
#pragma unroll
            for (int j = 0; j < 8; ++j) u[j] = G4[(size_t)s[j] * 64 + lane];
#pragma unroll
            for (int j = 0; j < 8; ++j) d[j] = rsqrtf((float)cnt[s[j]] + 1.0f);
#pragma unroll
            for (int j = 0; j < 8; j += 2) {
                float4 v0 = bf4_to_f4(u[j]);
                float4 v1 = bf4_to_f4(u[j + 1]);
                acc.x = fmaf(d[j], v0.x, acc.x);     acc.y = fmaf(d[j], v0.y, acc.y);
                acc.z = fmaf(d[j], v0.z, acc.z);     acc.w = fmaf(d[j], v0.w, acc.w);
                acc2.x = fmaf(d[j+1], v1.x, acc2.x); acc2.y = fmaf(d[j+1], v1.y, acc2.y);
                acc2.z = fmaf(d[j+1], v1.z, acc2.z); acc2.w = fmaf(d[j+1], v1.w, acc2.w);
            }
        }
        for (; e < deg; ++e) {
            int s0 = sl[e];
            float d0 = rsqrtf((float)cnt[s0] + 1.0f);
            float4 v0 = bf4_to_f4(G4[(size_t)s0 * 64 + lane]);
            acc.x = fmaf(d0, v0.x, acc.x); acc.y = fmaf(d0, v0.y, acc.y);
            acc.z = fmaf(d0, v0.z, acc.z); acc.w = fmaf(d0, v0.w, acc.w);
        }
        acc.x += acc2.x; acc.y += acc2.y; acc.z += acc2.z; acc.w += acc2.w;

        const float4 bv = ((const float4*)b1)[lane];
        float4 rr;
        rr.x = di * acc.x + bv.x;
        rr.y = di * acc.y + bv.y;
        rr.z = di * acc.z + bv.z;
        rr.w = di * acc.w + bv.w;
        rr.x = rr.x > 0.f ? rr.x : 0.f;
        rr.y = rr.y > 0.f ? rr.y : 0.f;
        rr.z = rr.z > 0.f ? rr.z : 0.f;
        rr.w = rr.w > 0.f ? rr.w : 0.f;

        ushort4 hv;
        hv.x = f2bf(rr.x); hv.y = f2bf(rr.y); hv.z = f2bf(rr.z); hv.w = f2bf(rr.w);
        // lane covers feats 4*lane..4*lane+3 -> 16B slot index lane>>1, swizzled by row&7
        int s0 = (lane >> 1) ^ (ln & 7);
        *(ushort4*)((char*)hs + ln * 512 + (s0 << 4) + (lane & 1) * 8) = hv;
    }
    __syncthreads();

    // ---- phase 2: 16x256 @ W2^T(128x256) -> 16x128; wave tile 16x32 ----
    const int r = lane & 15;
    const int kg = lane >> 4;
    const int wn = wid * 32;

    f32x4 acc[2];
    acc[0] = (f32x4){0.f, 0.f, 0.f, 0.f};
    acc[1] = (f32x4){0.f, 0.f, 0.f, 0.f};

    for (int k0 = 0; k0 < H_DIM; k0 += 32) {
        int slot = ((k0 >> 3) + kg) ^ (r & 7);
        bf16x8 a = *(const bf16x8*)((const char*)hs + r * 512 + (slot << 4));
#pragma unroll
        for (int ni = 0; ni < 2; ++ni) {
            size_t off = (size_t)(wn + ni * 16 + r) * H_DIM + k0 + kg * 8;
            bf16x8 bh = *(const bf16x8*)(w2th + off);
            bf16x8 bl = *(const bf16x8*)(w2tl + off);
            acc[ni] = __builtin_amdgcn_mfma_f32_16x16x32_bf16(a, bh, acc[ni], 0, 0, 0);
            acc[ni] = __builtin_amdgcn_mfma_f32_16x16x32_bf16(a, bl, acc[ni], 0, 0, 0);
        }
    }

    float di4[4];
#pragma unroll
    for (int i = 0; i < 4; ++i) di4[i] = rsqrtf((float)cnt[nb + kg * 4 + i] + 1.0f);
#pragma unroll
    for (int ni = 0; ni < 2; ++ni) {
#pragma unroll
        for (int i = 0; i < 4; ++i) {
            int row = nb + kg * 4 + i;
            g2b[(size_t)row * O_DIM + wn + ni * 16 + r] = f2bf(di4[i] * acc[ni][i]);
        }
    }
}

// ---------------- K4: fused gather layer 2 + head (ushort2 loads, 2-wave split) ----------------
__global__ __launch_bounds__(128) void gather_head_kernel(
    const unsigned short* __restrict__ g2,   // [8192][128] bf16, dinv-scaled
    const int* __restrict__ cnt, const int* __restrict__ slots,
    const float* __restrict__ b2,
    const float* __restrict__ Wmu, const float* __restrict__ bmu,
    const float* __restrict__ Wlv, const float* __restrict__ blv,
    const float* __restrict__ eps,
    float* __restrict__ mu_out, float* __restrict__ lv_out,
    _Float16* __restrict__ zr)
{
    __shared__ float zsw[2][O_DIM];
    __shared__ float zs[O_DIM];
    __shared__ float mu_s[C_DIM];
    __shared__ float lv_s[C_DIM];
    const int node = blockIdx.x;
    const int t = threadIdx.x;
    const int w = t >> 6;
    const int lane = t & 63;

    const int deg = cnt[node];
    const int* sl = slots + node * BCAP;
    const unsigned int* G2 = (const unsigned int*)g2;  // row stride 64 uints (128 bf16)

    float a0 = 0.f, a1 = 0.f, c0 = 0.f, c1 = 0.f;
    if (w == 0) {
        unsigned int u = G2[(size_t)node * 64 + lane];
        a0 = bf2f((unsigned short)u);
        a1 = bf2f((unsigned short)(u >> 16));
    }
    int e = w;
    for (; e + 6 < deg; e += 8) {
        unsigned int u0 = G2[(size_t)sl[e]     * 64 + lane];
        unsigned int u1 = G2[(size_t)sl[e + 2] * 64 + lane];
        unsigned int u2 = G2[(size_t)sl[e + 4] * 64 + lane];
        unsigned int u3 = G2[(size_t)sl[e + 6] * 64 + lane];
        a0 += bf2f((unsigned short)u0) + bf2f((unsigned short)u1);
        a1 += bf2f((unsigned short)(u0 >> 16)) + bf2f((unsigned short)(u1 >> 16));
        c0 += bf2f((unsigned short)u2) + bf2f((unsigned short)u3);
        c1 += bf2f((unsigned short)(u2 >> 16)) + bf2f((unsigned short)(u3 >> 16));
    }
    for (; e < deg; e += 2) {
        unsigned int u = G2[(size_t)sl[e] * 64 + lane];
        a0 += bf2f((unsigned short)u);
        a1 += bf2f((unsigned short)(u >> 16));
    }
    zsw[w][2 * lane]     = a0 + c0;
    zsw[w][2 * lane + 1] = a1 + c1;
    __syncthreads();

    float dv = rsqrtf((float)deg + 1.0f);
    zs[t] = dv * (zsw[0][t] + zsw[1][t]) + b2[t];
    __syncthreads();

    const int c = t & 63;
    const float* W = (t < 64) ? Wmu : Wlv;
    float s = 0.f;
#pragma unroll 8
    for (int k = 0; k < O_DIM; ++k) s += zs[k] * W[k * C_DIM + c];
    if (t < 64) {
        s += bmu[c];
        mu_out[(size_t)node * C_DIM + c] = s;
        mu_s[c] = s;
    } else {
        s += blv[c];
        lv_out[(size_t)node * C_DIM + c] = s;
        lv_s[c] = s;
    }
    __syncthreads();
    if (t < 64) {
        float stdv = __expf(0.5f * lv_s[c]);
        float v = mu_s[c] + eps[(size_t)node * C_DIM + c] * stdv;
        zr[(size_t)node * C_DIM + c] = (_Float16)v;
    }
}

// ---------------- K5: adj = sigmoid(zr @ zr^T) via fp16 MFMA, nontemporal stores ----------------
__global__ __launch_bounds__(256) void adj_mfma_kernel(
    const _Float16* __restrict__ Z, float* __restrict__ out)
{
    const int tid = threadIdx.x;
    const int lane = tid & 63;
    const int wid = tid >> 6;
    const int r = lane & 15;
    const int kg = lane >> 4;
    const int m0 = blockIdx.y * 128 + (wid >> 1) * 64;
    const int n0 = blockIdx.x * 128 + (wid & 1) * 64;

    f16x8 a[4][2], b[4][2];
#pragma unroll
    for (int mi = 0; mi < 4; ++mi)
#pragma unroll
        for (int ks = 0; ks < 2; ++ks) {
            a[mi][ks] = *(const f16x8*)(Z + (size_t)(m0 + mi * 16 + r) * C_DIM + ks * 32 + kg * 8);
            b[mi][ks] = *(const f16x8*)(Z + (size_t)(n0 + mi * 16 + r) * C_DIM + ks * 32 + kg * 8);
        }

    f32x4 acc[4][4];
#pragma unroll
    for (int mi = 0; mi < 4; ++mi)
#pragma unroll
        for (int ni = 0; ni < 4; ++ni) acc[mi][ni] = (f32x4){0.f, 0.f, 0.f, 0.f};

#pragma unroll
    for (int mi = 0; mi < 4; ++mi)
#pragma unroll
        for (int ni = 0; ni < 4; ++ni) {
            acc[mi][ni] = __builtin_amdgcn_mfma_f32_16x16x32_f16(a[mi][0], b[ni][0], acc[mi][ni], 0, 0, 0);
            acc[mi][ni] = __builtin_amdgcn_mfma_f32_16x16x32_f16(a[mi][1], b[ni][1], acc[mi][ni], 0, 0, 0);
        }

#pragma unroll
    for (int mi = 0; mi < 4; ++mi) {
        int rowb = m0 + mi * 16 + kg * 4;
#pragma unroll
        for (int ni = 0; ni < 4; ++ni) {
            int col = n0 + ni * 16 + r;
#pragma unroll
            for (int i = 0; i < 4; ++i) {
                float v = acc[mi][ni][i];
                float e = __expf(-v);
                float sg = __builtin_amdgcn_rcpf(1.0f + e);
                __builtin_nontemporal_store(sg, &out[(size_t)(rowb + i) * N_NODES + col]);
            }
        }
    }
}

extern "C" void kernel_launch(void* const* d_in, const int* in_sizes, int n_in,
                              void* d_out, int out_size, void* d_ws, size_t ws_size,
                              hipStream_t stream) {
    const float* x   = (const float*)d_in[0];
    const int*   ei  = (const int*)  d_in[1];
    const float* eps = (const float*)d_in[2];
    const float* W1  = (const float*)d_in[3];
    const float* b1  = (const float*)d_in[4];
    const float* W2  = (const float*)d_in[5];
    const float* b2  = (const float*)d_in[6];
    const float* Wmu = (const float*)d_in[7];
    const float* bmu = (const float*)d_in[8];
    const float* Wlv = (const float*)d_in[9];
    const float* blv = (const float*)d_in[10];
    float* out = (float*)d_out;

    const int* srcv = ei;
    const int* dstv = ei + E_EDGES;

    char* p = (char*)d_ws;
    auto carve = [&](size_t bytes) -> void* {
        void* q = (void*)p;
        p += (bytes + 255) & ~(size_t)255;
        return q;
    };
    int* cnt      = (int*)carve(N_NODES * 4);
    int* slots    = (int*)carve((size_t)N_NODES * BCAP * 4);
    unsigned short* w1th = (unsigned short*)carve((size_t)F_IN * H_DIM * 2);
    unsigned short* w1tl = (unsigned short*)carve((size_t)F_IN * H_DIM * 2);
    unsigned short* w2th = (unsigned short*)carve((size_t)H_DIM * O_DIM * 2);
    unsigned short* w2tl = (unsigned short*)carve((size_t)H_DIM * O_DIM * 2);
    unsigned short* raw1 = (unsigned short*)carve((size_t)N_NODES * H_DIM * 2);
    unsigned short* g2b  = (unsigned short*)carve((size_t)N_NODES * O_DIM * 2);
    _Float16* zr         = (_Float16*)carve((size_t)N_NODES * C_DIM * 2);

    float* mu_out = out + (size_t)N_NODES * N_NODES;
    float* lv_out = mu_out + (size_t)N_NODES * C_DIM;

    // ---- 1. prep: cnt zero + weight transposed splits ----
    {
        const int total = F_IN * H_DIM + H_DIM * O_DIM;  // 163840 (>= N_NODES)
        prep_kernel<<<(total + 255) / 256, 256, 0, stream>>>(
            W1, w1th, w1tl, W2, w2th, w2tl, cnt);
    }

    // ---- 2. gemm1: edge bucket-fill + raw1 = bf16(x)@W1(hi/lo), 64x128 tiles ----
    {
        dim3 grid(H_DIM / 128, N_NODES / 64);   // 2 x 128 = 256 blocks
        gemm1_kernel<<<grid, 256, 0, stream>>>(
            x, w1th, w1tl, srcv, dstv, cnt, slots, raw1);
    }

    // ---- 3. fused gather1 + gemm2 -> g2b ----
    gather_gemm2_kernel<<<N_NODES / 16, 256, 0, stream>>>(
        raw1, cnt, slots, b1, w2th, w2tl, g2b);

    // ---- 4. fused gather 2 + head (zr fp16) ----
    gather_head_kernel<<<N_NODES, 128, 0, stream>>>(
        g2b, cnt, slots, b2, Wmu, bmu, Wlv, blv, eps,
        mu_out, lv_out, zr);

    // ---- 5. adjacency reconstruction (fp16 MFMA) ----
    {
        dim3 grid(N_NODES / 128, N_NODES / 128);
        adj_mfma_kernel<<<grid, 256, 0, stream>>>(zr, out);
    }
}

// Round 11
// 173.661 us; speedup vs baseline: 1.2080x; 1.0351x over previous
//
#include <hip/hip_runtime.h>
#include <hip/hip_bf16.h>

#define N_NODES 8192
#define F_IN    512
#define H_DIM   256
#define O_DIM   128
#define C_DIM   64
#define E_EDGES 262144
#define BCAP    96

typedef __attribute__((ext_vector_type(8))) short bf16x8;
typedef __attribute__((ext_vector_type(8))) _Float16 f16x8;
typedef __attribute__((ext_vector_type(4))) float f32x4;

__device__ inline unsigned short f2bf(float v) {
    __hip_bfloat16 h = __float2bfloat16(v);
    return *reinterpret_cast<unsigned short*>(&h);
}
__device__ inline float bf2f(unsigned short u) {
    return __uint_as_float((unsigned)u << 16);
}
__device__ inline void split2(float v, unsigned short& hi, unsigned short& lo) {
    hi = f2bf(v);
    lo = f2bf(v - bf2f(hi));
}
__device__ inline float4 bf4_to_f4(ushort4 u) {
    float4 f;
    f.x = bf2f(u.x); f.y = bf2f(u.y); f.z = bf2f(u.z); f.w = bf2f(u.w);
    return f;
}

// ---------------- K1: prep — zero cnt; x -> bf16; W1 -> W1^T bf16; W2 -> W2^T hi/lo ----------------
__global__ __launch_bounds__(256) void prep_kernel(
    const float* __restrict__ x, unsigned short* __restrict__ xb,
    const float* __restrict__ W1, unsigned short* __restrict__ w1t,
    const float* __restrict__ W2, unsigned short* __restrict__ w2th, unsigned short* __restrict__ w2tl,
    int* __restrict__ cnt)
{
    const int NX4 = N_NODES * F_IN / 4;       // 1048576
    const int NW1 = F_IN * H_DIM;             // 131072
    const int NW2 = H_DIM * O_DIM;            // 32768
    int idx = blockIdx.x * 256 + threadIdx.x;
    if (idx < N_NODES) cnt[idx] = 0;
    if (idx < NX4) {
        float4 v = ((const float4*)x)[idx];
        ushort4 b;
        b.x = f2bf(v.x); b.y = f2bf(v.y); b.z = f2bf(v.z); b.w = f2bf(v.w);
        ((ushort4*)xb)[idx] = b;
    } else if (idx < NX4 + NW1) {
        int j = idx - NX4;
        int k = j / H_DIM, n = j % H_DIM;
        w1t[n * F_IN + k] = f2bf(W1[j]);
    } else if (idx < NX4 + NW1 + NW2) {
        int j = idx - NX4 - NW1;
        int k = j / O_DIM, n = j % O_DIM;
        unsigned short h, l;
        split2(W2[j], h, l);
        w2th[n * H_DIM + k] = h;
        w2tl[n * H_DIM + k] = l;
    }
}

// ---------------- K2: gemm1 — edge bucket-fill + raw1 = bf16(xb @ w1t^T) ----------------
// Block tile 64x64 (waves 2x2, wave tile 32x32). grid (4, 128) = 512 blocks, 2 blocks/CU.
__global__ __launch_bounds__(256) void gemm1_kernel(
    const unsigned short* __restrict__ xb,
    const unsigned short* __restrict__ Bt,
    const int* __restrict__ srcv, const int* __restrict__ dstv,
    int* __restrict__ cnt, int* __restrict__ slots,
    unsigned short* __restrict__ out)   // raw1 [N_NODES][H_DIM]
{
    // edge fill: exactly 2 edges per thread (512 blocks * 256 thr * 2 = 262144)
    {
        int flat = (blockIdx.y * gridDim.x + blockIdx.x) * 256 + threadIdx.x;
        int e0 = flat * 2;
#pragma unroll
        for (int j = 0; j < 2; ++j) {
            int d = dstv[e0 + j];
            int pos = atomicAdd(&cnt[d], 1);
            slots[d * BCAP + pos] = srcv[e0 + j];
        }
    }

    constexpr int N = H_DIM, K = F_IN, MW = 2, NW = 2;
    const int tid = threadIdx.x;
    const int lane = tid & 63;
    const int wid = tid >> 6;
    const int r = lane & 15;
    const int kg = lane >> 4;
    const int m0 = blockIdx.y * (2 * MW * 16) + (wid >> 1) * (MW * 16);
    const int n0 = blockIdx.x * (2 * NW * 16) + (wid & 1) * (NW * 16);

    f32x4 acc[MW][NW];
#pragma unroll
    for (int mi = 0; mi < MW; ++mi)
#pragma unroll
        for (int ni = 0; ni < NW; ++ni) acc[mi][ni] = (f32x4){0.f, 0.f, 0.f, 0.f};

    for (int k0 = 0; k0 < K; k0 += 32) {
        const int kof = k0 + kg * 8;
        bf16x8 a[MW], b[NW];
#pragma unroll
        for (int mi = 0; mi < MW; ++mi)
            a[mi] = *(const bf16x8*)(xb + (size_t)(m0 + mi * 16 + r) * K + kof);
#pragma unroll
        for (int ni = 0; ni < NW; ++ni)
            b[ni] = *(const bf16x8*)(Bt + (size_t)(n0 + ni * 16 + r) * K + kof);
#pragma unroll
        for (int mi = 0; mi < MW; ++mi)
#pragma unroll
            for (int ni = 0; ni < NW; ++ni)
                acc[mi][ni] = __builtin_amdgcn_mfma_f32_16x16x32_bf16(a[mi], b[ni], acc[mi][ni], 0, 0, 0);
    }

#pragma unroll
    for (int mi = 0; mi < MW; ++mi) {
        int rowb = m0 + mi * 16 + kg * 4;
#pragma unroll
        for (int ni = 0; ni < NW; ++ni) {
            int col = n0 + ni * 16 + r;
#pragma unroll
            for (int i = 0; i < 4; ++i)
                out[(size_t)(rowb + i) * N + col] = f2bf(acc[mi][ni][i]);
        }
    }
}

// ---------------- K3: fused gather1 + gemm2 ----------------
__global__ __launch_bounds__(256) void gather_gemm2_kernel(
    const unsigned short* __restrict__ raw,   // raw1 [8192][256] bf16, unscaled
    const int* __restrict__ cnt, const int* __restrict__ slots,
    const float* __restrict__ b1,
    const unsigned short* __restrict__ w2th, const unsigned short* __restrict__ w2tl,
    unsigned short* __restrict__ g2b)         // [8192][128] bf16, dinv-scaled
{
    __shared__ unsigned short hs[16 * 256];   // 8 KB, row stride 512 B, XOR-swizzled slots
    const int tid = threadIdx.x;
    const int wid = tid >> 6;
    const int lane = tid & 63;
    const int nb = blockIdx.x * 16;
    const ushort4* G4 = (const ushort4*)raw;

    // ---- phase 1: each wave gathers 4 node rows ----
    for (int q = 0; q < 4; ++q) {
        const int ln = wid * 4 + q;
        const int node = nb + ln;
        const int deg = cnt[node];
        const int* sl = slots + node * BCAP;
        const float di = rsqrtf((float)deg + 1.0f);

        float4 selfv = bf4_to_f4(G4[(size_t)node * 64 + lane]);
        float4 acc, acc2;
        acc.x = di * selfv.x; acc.y = di * selfv.y;
        acc.z = di * selfv.z; acc.w = di * selfv.w;
        acc2 = make_float4(0.f, 0.f, 0.f, 0.f);

        int e = 0;
        for (; e + 8 <= deg; e += 8) {
            int s[8];
            ushort4 u[8];
            float d[8];
#pragma unroll
            for (int j = 0; j < 8; ++j) s[j] = sl[e + j];
#pragma unroll
            for (int j = 0; j < 8; ++j) u[j] = G4[(size_t)s[j] * 64 + lane];
#pragma unroll
            for (int j = 0; j < 8; ++j) d[j] = rsqrtf((float)cnt[s[j]] + 1.0f);
#pragma unroll
            for (int j = 0; j < 8; j += 2) {
                float4 v0 = bf4_to_f4(u[j]);
                float4 v1 = bf4_to_f4(u[j + 1]);
                acc.x = fmaf(d[j], v0.x, acc.x);     acc.y = fmaf(d[j], v0.y, acc.y);
                acc.z = fmaf(d[j], v0.z, acc.z);     acc.w = fmaf(d[j], v0.w, acc.w);
                acc2.x = fmaf(d[j+1], v1.x, acc2.x); acc2.y = fmaf(d[j+1], v1.y, acc2.y);
                acc2.z = fmaf(d[j+1], v1.z, acc2.z); acc2.w = fmaf(d[j+1], v1.w, acc2.w);
            }
        }
        for (; e < deg; ++e) {
            int s0 = sl[e];
            float d0 = rsqrtf((float)cnt[s0] + 1.0f);
            float4 v0 = bf4_to_f4(G4[(size_t)s0 * 64 + lane]);
            acc.x = fmaf(d0, v0.x, acc.x); acc.y = fmaf(d0, v0.y, acc.y);
            acc.z = fmaf(d0, v0.z, acc.z); acc.w = fmaf(d0, v0.w, acc.w);
        }
        acc.x += acc2.x; acc.y += acc2.y; acc.z += acc2.z; acc.w += acc2.w;

        const float4 bv = ((const float4*)b1)[lane];
        float4 rr;
        rr.x = di * acc.x + bv.x;
        rr.y = di * acc.y + bv.y;
        rr.z = di * acc.z + bv.z;
        rr.w = di * acc.w + bv.w;
        rr.x = rr.x > 0.f ? rr.x : 0.f;
        rr.y = rr.y > 0.f ? rr.y : 0.f;
        rr.z = rr.z > 0.f ? rr.z : 0.f;
        rr.w = rr.w > 0.f ? rr.w : 0.f;

        ushort4 hv;
        hv.x = f2bf(rr.x); hv.y = f2bf(rr.y); hv.z = f2bf(rr.z); hv.w = f2bf(rr.w);
        int s0 = (lane >> 1) ^ (ln & 7);
        *(ushort4*)((char*)hs + ln * 512 + (s0 << 4) + (lane & 1) * 8) = hv;
    }
    __syncthreads();

    // ---- phase 2: 16x256 @ W2^T(128x256) -> 16x128; wave tile 16x32 ----
    const int r = lane & 15;
    const int kg = lane >> 4;
    const int wn = wid * 32;

    f32x4 acc[2];
    acc[0] = (f32x4){0.f, 0.f, 0.f, 0.f};
    acc[1] = (f32x4){0.f, 0.f, 0.f, 0.f};

    for (int k0 = 0; k0 < H_DIM; k0 += 32) {
        int slot = ((k0 >> 3) + kg) ^ (r & 7);
        bf16x8 a = *(const bf16x8*)((const char*)hs + r * 512 + (slot << 4));
#pragma unroll
        for (int ni = 0; ni < 2; ++ni) {
            size_t off = (size_t)(wn + ni * 16 + r) * H_DIM + k0 + kg * 8;
            bf16x8 bh = *(const bf16x8*)(w2th + off);
            bf16x8 bl = *(const bf16x8*)(w2tl + off);
            acc[ni] = __builtin_amdgcn_mfma_f32_16x16x32_bf16(a, bh, acc[ni], 0, 0, 0);
            acc[ni] = __builtin_amdgcn_mfma_f32_16x16x32_bf16(a, bl, acc[ni], 0, 0, 0);
        }
    }

    float di4[4];
#pragma unroll
    for (int i = 0; i < 4; ++i) di4[i] = rsqrtf((float)cnt[nb + kg * 4 + i] + 1.0f);
#pragma unroll
    for (int ni = 0; ni < 2; ++ni) {
#pragma unroll
        for (int i = 0; i < 4; ++i) {
            int row = nb + kg * 4 + i;
            g2b[(size_t)row * O_DIM + wn + ni * 16 + r] = f2bf(di4[i] * acc[ni][i]);
        }
    }
}

// ---------------- K4: fused gather layer 2 + head (ushort2 loads, 2-wave split) ----------------
__global__ __launch_bounds__(128) void gather_head_kernel(
    const unsigned short* __restrict__ g2,   // [8192][128] bf16, dinv-scaled
    const int* __restrict__ cnt, const int* __restrict__ slots,
    const float* __restrict__ b2,
    const float* __restrict__ Wmu, const float* __restrict__ bmu,
    const float* __restrict__ Wlv, const float* __restrict__ blv,
    const float* __restrict__ eps,
    float* __restrict__ mu_out, float* __restrict__ lv_out,
    _Float16* __restrict__ zr)
{
    __shared__ float zsw[2][O_DIM];
    __shared__ float zs[O_DIM];
    __shared__ float mu_s[C_DIM];
    __shared__ float lv_s[C_DIM];
    const int node = blockIdx.x;
    const int t = threadIdx.x;
    const int w = t >> 6;
    const int lane = t & 63;

    const int deg = cnt[node];
    const int* sl = slots + node * BCAP;
    const unsigned int* G2 = (const unsigned int*)g2;  // row stride 64 uints (128 bf16)

    float a0 = 0.f, a1 = 0.f, c0 = 0.f, c1 = 0.f;
    if (w == 0) {
        unsigned int u = G2[(size_t)node * 64 + lane];
        a0 = bf2f((unsigned short)u);
        a1 = bf2f((unsigned short)(u >> 16));
    }
    int e = w;
    for (; e + 6 < deg; e += 8) {
        unsigned int u0 = G2[(size_t)sl[e]     * 64 + lane];
        unsigned int u1 = G2[(size_t)sl[e + 2] * 64 + lane];
        unsigned int u2 = G2[(size_t)sl[e + 4] * 64 + lane];
        unsigned int u3 = G2[(size_t)sl[e + 6] * 64 + lane];
        a0 += bf2f((unsigned short)u0) + bf2f((unsigned short)u1);
        a1 += bf2f((unsigned short)(u0 >> 16)) + bf2f((unsigned short)(u1 >> 16));
        c0 += bf2f((unsigned short)u2) + bf2f((unsigned short)u3);
        c1 += bf2f((unsigned short)(u2 >> 16)) + bf2f((unsigned short)(u3 >> 16));
    }
    for (; e < deg; e += 2) {
        unsigned int u = G2[(size_t)sl[e] * 64 + lane];
        a0 += bf2f((unsigned short)u);
        a1 += bf2f((unsigned short)(u >> 16));
    }
    zsw[w][2 * lane]     = a0 + c0;
    zsw[w][2 * lane + 1] = a1 + c1;
    __syncthreads();

    float dv = rsqrtf((float)deg + 1.0f);
    zs[t] = dv * (zsw[0][t] + zsw[1][t]) + b2[t];
    __syncthreads();

    const int c = t & 63;
    const float* W = (t < 64) ? Wmu : Wlv;
    float s = 0.f;
#pragma unroll 8
    for (int k = 0; k < O_DIM; ++k) s += zs[k] * W[k * C_DIM + c];
    if (t < 64) {
        s += bmu[c];
        mu_out[(size_t)node * C_DIM + c] = s;
        mu_s[c] = s;
    } else {
        s += blv[c];
        lv_out[(size_t)node * C_DIM + c] = s;
        lv_s[c] = s;
    }
    __syncthreads();
    if (t < 64) {
        float stdv = __expf(0.5f * lv_s[c]);
        float v = mu_s[c] + eps[(size_t)node * C_DIM + c] * stdv;
        zr[(size_t)node * C_DIM + c] = (_Float16)v;
    }
}

// ---------------- K5: adj = sigmoid(zr @ zr^T) via fp16 MFMA, nontemporal stores ----------------
__global__ __launch_bounds__(256) void adj_mfma_kernel(
    const _Float16* __restrict__ Z, float* __restrict__ out)
{
    const int tid = threadIdx.x;
    const int lane = tid & 63;
    const int wid = tid >> 6;
    const int r = lane & 15;
    const int kg = lane >> 4;
    const int m0 = blockIdx.y * 128 + (wid >> 1) * 64;
    const int n0 = blockIdx.x * 128 + (wid & 1) * 64;

    f16x8 a[4][2], b[4][2];
#pragma unroll
    for (int mi = 0; mi < 4; ++mi)
#pragma unroll
        for (int ks = 0; ks < 2; ++ks) {
            a[mi][ks] = *(const f16x8*)(Z + (size_t)(m0 + mi * 16 + r) * C_DIM + ks * 32 + kg * 8);
            b[mi][ks] = *(const f16x8*)(Z + (size_t)(n0 + mi * 16 + r) * C_DIM + ks * 32 + kg * 8);
        }

    f32x4 acc[4][4];
#pragma unroll
    for (int mi = 0; mi < 4; ++mi)
#pragma unroll
        for (int ni = 0; ni < 4; ++ni) acc[mi][ni] = (f32x4){0.f, 0.f, 0.f, 0.f};

#pragma unroll
    for (int mi = 0; mi < 4; ++mi)
#pragma unroll
        for (int ni = 0; ni < 4; ++ni) {
            acc[mi][ni] = __builtin_amdgcn_mfma_f32_16x16x32_f16(a[mi][0], b[ni][0], acc[mi][ni], 0, 0, 0);
            acc[mi][ni] = __builtin_amdgcn_mfma_f32_16x16x32_f16(a[mi][1], b[ni][1], acc[mi][ni], 0, 0, 0);
        }

#pragma unroll
    for (int mi = 0; mi < 4; ++mi) {
        int rowb = m0 + mi * 16 + kg * 4;
#pragma unroll
        for (int ni = 0; ni < 4; ++ni) {
            int col = n0 + ni * 16 + r;
#pragma unroll
            for (int i = 0; i < 4; ++i) {
                float v = acc[mi][ni][i];
                float e = __expf(-v);
                float sg = __builtin_amdgcn_rcpf(1.0f + e);
                __builtin_nontemporal_store(sg, &out[(size_t)(rowb + i) * N_NODES + col]);
            }
        }
    }
}

extern "C" void kernel_launch(void* const* d_in, const int* in_sizes, int n_in,
                              void* d_out, int out_size, void* d_ws, size_t ws_size,
                              hipStream_t stream) {
    const float* x   = (const float*)d_in[0];
    const int*   ei  = (const int*)  d_in[1];
    const float* eps = (const float*)d_in[2];
    const float* W1  = (const float*)d_in[3];
    const float* b1  = (const float*)d_in[4];
    const float* W2  = (const float*)d_in[5];
    const float* b2  = (const float*)d_in[6];
    const float* Wmu = (const float*)d_in[7];
    const float* bmu = (const float*)d_in[8];
    const float* Wlv = (const float*)d_in[9];
    const float* blv = (const float*)d_in[10];
    float* out = (float*)d_out;

    const int* srcv = ei;
    const int* dstv = ei + E_EDGES;

    char* p = (char*)d_ws;
    auto carve = [&](size_t bytes) -> void* {
        void* q = (void*)p;
        p += (bytes + 255) & ~(size_t)255;
        return q;
    };
    int* cnt      = (int*)carve(N_NODES * 4);
    int* slots    = (int*)carve((size_t)N_NODES * BCAP * 4);
    unsigned short* xb   = (unsigned short*)carve((size_t)N_NODES * F_IN * 2);
    unsigned short* w1t  = (unsigned short*)carve((size_t)F_IN * H_DIM * 2);
    unsigned short* w2th = (unsigned short*)carve((size_t)H_DIM * O_DIM * 2);
    unsigned short* w2tl = (unsigned short*)carve((size_t)H_DIM * O_DIM * 2);
    unsigned short* raw1 = (unsigned short*)carve((size_t)N_NODES * H_DIM * 2);
    unsigned short* g2b  = (unsigned short*)carve((size_t)N_NODES * O_DIM * 2);
    _Float16* zr         = (_Float16*)carve((size_t)N_NODES * C_DIM * 2);

    float* mu_out = out + (size_t)N_NODES * N_NODES;
    float* lv_out = mu_out + (size_t)N_NODES * C_DIM;

    // ---- 1. prep: cnt zero + x->bf16 + W1^T bf16 + W2^T hi/lo ----
    {
        const int total = N_NODES * F_IN / 4 + F_IN * H_DIM + H_DIM * O_DIM;  // 1212416
        prep_kernel<<<(total + 255) / 256, 256, 0, stream>>>(
            x, xb, W1, w1t, W2, w2th, w2tl, cnt);
    }

    // ---- 2. gemm1: edge bucket-fill + raw1 = xb@w1t^T, 64x64 tiles, 512 blocks ----
    {
        dim3 grid(H_DIM / 64, N_NODES / 64);   // 4 x 128 = 512 blocks
        gemm1_kernel<<<grid, 256, 0, stream>>>(
            xb, w1t, srcv, dstv, cnt, slots, raw1);
    }

    // ---- 3. fused gather1 + gemm2 -> g2b ----
    gather_gemm2_kernel<<<N_NODES / 16, 256, 0, stream>>>(
        raw1, cnt, slots, b1, w2th, w2tl, g2b);

    // ---- 4. fused gather 2 + head (zr fp16) ----
    gather_head_kernel<<<N_NODES, 128, 0, stream>>>(
        g2b, cnt, slots, b2, Wmu, bmu, Wlv, blv, eps,
        mu_out, lv_out, zr);

    // ---- 5. adjacency reconstruction (fp16 MFMA) ----
    {
        dim3 grid(N_NODES / 128, N_NODES / 128);
        adj_mfma_kernel<<<grid, 256, 0, stream>>>(zr, out);
    }
}

// Round 12
// 166.293 us; speedup vs baseline: 1.2615x; 1.0443x over previous
//
#include <hip/hip_runtime.h>
#include <hip/hip_bf16.h>

#define N_NODES 8192
#define F_IN    512
#define H_DIM   256
#define O_DIM   128
#define C_DIM   64
#define E_EDGES 262144
#define BCAP    96

typedef __attribute__((ext_vector_type(8))) short bf16x8;
typedef __attribute__((ext_vector_type(8))) _Float16 f16x8;
typedef __attribute__((ext_vector_type(4))) float f32x4;

__device__ inline unsigned short f2bf(float v) {
    __hip_bfloat16 h = __float2bfloat16(v);
    return *reinterpret_cast<unsigned short*>(&h);
}
__device__ inline float bf2f(unsigned short u) {
    return __uint_as_float((unsigned)u << 16);
}
__device__ inline float4 bf4_to_f4(ushort4 u) {
    float4 f;
    f.x = bf2f(u.x); f.y = bf2f(u.y); f.z = bf2f(u.z); f.w = bf2f(u.w);
    return f;
}
__device__ inline bf16x8 pack_bf8(float4 a, float4 b) {
    bf16x8 r;
    r[0] = (short)f2bf(a.x); r[1] = (short)f2bf(a.y);
    r[2] = (short)f2bf(a.z); r[3] = (short)f2bf(a.w);
    r[4] = (short)f2bf(b.x); r[5] = (short)f2bf(b.y);
    r[6] = (short)f2bf(b.z); r[7] = (short)f2bf(b.w);
    return r;
}

// ---------------- K1: prep — zero cnt; W1 -> W1^T bf16; W2 -> W2^T bf16 ----------------
__global__ __launch_bounds__(256) void prep_kernel(
    const float* __restrict__ W1, unsigned short* __restrict__ w1t,
    const float* __restrict__ W2, unsigned short* __restrict__ w2t,
    int* __restrict__ cnt)
{
    const int NW1 = F_IN * H_DIM;             // 131072
    const int NW2 = H_DIM * O_DIM;            // 32768
    int idx = blockIdx.x * 256 + threadIdx.x;
    if (idx < N_NODES) cnt[idx] = 0;
    if (idx < NW1) {
        int k = idx / H_DIM, n = idx % H_DIM;
        w1t[n * F_IN + k] = f2bf(W1[idx]);
    } else if (idx < NW1 + NW2) {
        int j = idx - NW1;
        int k = j / O_DIM, n = j % O_DIM;
        w2t[n * H_DIM + k] = f2bf(W2[j]);
    }
}

// ---------------- K2: gemm1 — edge bucket-fill + raw1 = bf16(bf16(x) @ w1t^T) ----------------
// x read fp32, packed to bf16 in-register. 64x64 tiles, grid (4,128) = 512 blocks.
__global__ __launch_bounds__(256) void gemm1_kernel(
    const float* __restrict__ x,
    const unsigned short* __restrict__ Bt,
    const int* __restrict__ srcv, const int* __restrict__ dstv,
    int* __restrict__ cnt, int* __restrict__ slots,
    unsigned short* __restrict__ out)   // raw1 [N_NODES][H_DIM]
{
    // edge fill: exactly 2 edges per thread (512 blocks * 256 thr * 2 = 262144)
    {
        int flat = (blockIdx.y * gridDim.x + blockIdx.x) * 256 + threadIdx.x;
        int e0 = flat * 2;
#pragma unroll
        for (int j = 0; j < 2; ++j) {
            int d = dstv[e0 + j];
            int pos = atomicAdd(&cnt[d], 1);
            slots[d * BCAP + pos] = srcv[e0 + j];
        }
    }

    constexpr int N = H_DIM, K = F_IN, MW = 2, NW = 2;
    const int tid = threadIdx.x;
    const int lane = tid & 63;
    const int wid = tid >> 6;
    const int r = lane & 15;
    const int kg = lane >> 4;
    const int m0 = blockIdx.y * (2 * MW * 16) + (wid >> 1) * (MW * 16);
    const int n0 = blockIdx.x * (2 * NW * 16) + (wid & 1) * (NW * 16);

    f32x4 acc[MW][NW];
#pragma unroll
    for (int mi = 0; mi < MW; ++mi)
#pragma unroll
        for (int ni = 0; ni < NW; ++ni) acc[mi][ni] = (f32x4){0.f, 0.f, 0.f, 0.f};

    for (int k0 = 0; k0 < K; k0 += 32) {
        const int kof = k0 + kg * 8;
        bf16x8 a[MW], b[NW];
#pragma unroll
        for (int mi = 0; mi < MW; ++mi) {
            const float* xr = x + (size_t)(m0 + mi * 16 + r) * K + kof;
            float4 f0 = *(const float4*)xr;
            float4 f1 = *(const float4*)(xr + 4);
            a[mi] = pack_bf8(f0, f1);
        }
#pragma unroll
        for (int ni = 0; ni < NW; ++ni)
            b[ni] = *(const bf16x8*)(Bt + (size_t)(n0 + ni * 16 + r) * K + kof);
#pragma unroll
        for (int mi = 0; mi < MW; ++mi)
#pragma unroll
            for (int ni = 0; ni < NW; ++ni)
                acc[mi][ni] = __builtin_amdgcn_mfma_f32_16x16x32_bf16(a[mi], b[ni], acc[mi][ni], 0, 0, 0);
    }

#pragma unroll
    for (int mi = 0; mi < MW; ++mi) {
        int rowb = m0 + mi * 16 + kg * 4;
#pragma unroll
        for (int ni = 0; ni < NW; ++ni) {
            int col = n0 + ni * 16 + r;
#pragma unroll
            for (int i = 0; i < 4; ++i)
                out[(size_t)(rowb + i) * N + col] = f2bf(acc[mi][ni][i]);
        }
    }
}

// ---------------- K3: fused gather1 + gemm2 (512 threads, 8 waves) ----------------
// Phase 1: each wave gathers 2 node rows (relu GCN) into XOR-swizzled LDS (bf16).
// Phase 2: each wave computes one 16(node)x16(col) output fragment per 16-col chunk.
__global__ __launch_bounds__(512) void gather_gemm2_kernel(
    const unsigned short* __restrict__ raw,   // raw1 [8192][256] bf16, unscaled
    const int* __restrict__ cnt, const int* __restrict__ slots,
    const float* __restrict__ b1,
    const unsigned short* __restrict__ w2t,
    unsigned short* __restrict__ g2b)         // [8192][128] bf16, dinv-scaled
{
    __shared__ unsigned short hs[16 * 256];   // 8 KB, row stride 512 B, XOR-swizzled 16B slots
    const int tid = threadIdx.x;
    const int wid = tid >> 6;                 // 0..7
    const int lane = tid & 63;
    const int nb = blockIdx.x * 16;
    const ushort4* G4 = (const ushort4*)raw;

    // ---- phase 1: each wave gathers 2 node rows ----
    for (int q = 0; q < 2; ++q) {
        const int ln = wid * 2 + q;
        const int node = nb + ln;
        const int deg = cnt[node];
        const int* sl = slots + node * BCAP;
        const float di = rsqrtf((float)deg + 1.0f);

        float4 selfv = bf4_to_f4(G4[(size_t)node * 64 + lane]);
        float4 acc, acc2;
        acc.x = di * selfv.x; acc.y = di * selfv.y;
        acc.z = di * selfv.z; acc.w = di * selfv.w;
        acc2 = make_float4(0.f, 0.f, 0.f, 0.f);

        int e = 0;
        for (; e + 8 <= deg; e += 8) {
            int s[8];
            ushort4 u[8];
            float d[8];
#pragma unroll
            for (int j = 0; j < 8; ++j) s[j] = sl[e + j];
#pragma unroll
            for (int j = 0; j < 8; ++j) u[j] = G4[(size_t)s[j] * 64 + lane];
#pragma unroll
            for (int j = 0; j < 8; ++j) d[j] = rsqrtf((float)cnt[s[j]] + 1.0f);
#pragma unroll
            for (int j = 0; j < 8; j += 2) {
                float4 v0 = bf4_to_f4(u[j]);
                float4 v1 = bf4_to_f4(u[j + 1]);
                acc.x = fmaf(d[j], v0.x, acc.x);     acc.y = fmaf(d[j], v0.y, acc.y);
                acc.z = fmaf(d[j], v0.z, acc.z);     acc.w = fmaf(d[j], v0.w, acc.w);
                acc2.x = fmaf(d[j+1], v1.x, acc2.x); acc2.y = fmaf(d[j+1], v1.y, acc2.y);
                acc2.z = fmaf(d[j+1], v1.z, acc2.z); acc2.w = fmaf(d[j+1], v1.w, acc2.w);
            }
        }
        for (; e < deg; ++e) {
            int s0 = sl[e];
            float d0 = rsqrtf((float)cnt[s0] + 1.0f);
            float4 v0 = bf4_to_f4(G4[(size_t)s0 * 64 + lane]);
            acc.x = fmaf(d0, v0.x, acc.x); acc.y = fmaf(d0, v0.y, acc.y);
            acc.z = fmaf(d0, v0.z, acc.z); acc.w = fmaf(d0, v0.w, acc.w);
        }
        acc.x += acc2.x; acc.y += acc2.y; acc.z += acc2.z; acc.w += acc2.w;

        const float4 bv = ((const float4*)b1)[lane];
        float4 rr;
        rr.x = di * acc.x + bv.x;
        rr.y = di * acc.y + bv.y;
        rr.z = di * acc.z + bv.z;
        rr.w = di * acc.w + bv.w;
        rr.x = rr.x > 0.f ? rr.x : 0.f;
        rr.y = rr.y > 0.f ? rr.y : 0.f;
        rr.z = rr.z > 0.f ? rr.z : 0.f;
        rr.w = rr.w > 0.f ? rr.w : 0.f;

        ushort4 hv;
        hv.x = f2bf(rr.x); hv.y = f2bf(rr.y); hv.z = f2bf(rr.z); hv.w = f2bf(rr.w);
        int s0 = (lane >> 1) ^ (ln & 7);
        *(ushort4*)((char*)hs + ln * 512 + (s0 << 4) + (lane & 1) * 8) = hv;
    }
    __syncthreads();

    // ---- phase 2: 16x256 @ W2^T(128x256) -> 16x128; wave wid covers cols wid*16..+15 ----
    const int r = lane & 15;
    const int kg = lane >> 4;
    const int wn = wid * 16;

    f32x4 acc = (f32x4){0.f, 0.f, 0.f, 0.f};
    for (int k0 = 0; k0 < H_DIM; k0 += 32) {
        int slot = ((k0 >> 3) + kg) ^ (r & 7);
        bf16x8 a = *(const bf16x8*)((const char*)hs + r * 512 + (slot << 4));
        bf16x8 b = *(const bf16x8*)(w2t + (size_t)(wn + r) * H_DIM + k0 + kg * 8);
        acc = __builtin_amdgcn_mfma_f32_16x16x32_bf16(a, b, acc, 0, 0, 0);
    }

#pragma unroll
    for (int i = 0; i < 4; ++i) {
        int row = nb + kg * 4 + i;
        float di = rsqrtf((float)cnt[row] + 1.0f);
        g2b[(size_t)row * O_DIM + wn + r] = f2bf(di * acc[i]);
    }
}

// ---------------- K4: fused gather layer 2 + head (ushort2 loads, 2-wave split) ----------------
__global__ __launch_bounds__(128) void gather_head_kernel(
    const unsigned short* __restrict__ g2,   // [8192][128] bf16, dinv-scaled
    const int* __restrict__ cnt, const int* __restrict__ slots,
    const float* __restrict__ b2,
    const float* __restrict__ Wmu, const float* __restrict__ bmu,
    const float* __restrict__ Wlv, const float* __restrict__ blv,
    const float* __restrict__ eps,
    float* __restrict__ mu_out, float* __restrict__ lv_out,
    _Float16* __restrict__ zr)
{
    __shared__ float zsw[2][O_DIM];
    __shared__ float zs[O_DIM];
    __shared__ float mu_s[C_DIM];
    __shared__ float lv_s[C_DIM];
    const int node = blockIdx.x;
    const int t = threadIdx.x;
    const int w = t >> 6;
    const int lane = t & 63;

    const int deg = cnt[node];
    const int* sl = slots + node * BCAP;
    const unsigned int* G2 = (const unsigned int*)g2;  // row stride 64 uints (128 bf16)

    float a0 = 0.f, a1 = 0.f, c0 = 0.f, c1 = 0.f;
    if (w == 0) {
        unsigned int u = G2[(size_t)node * 64 + lane];
        a0 = bf2f((unsigned short)u);
        a1 = bf2f((unsigned short)(u >> 16));
    }
    int e = w;
    for (; e + 6 < deg; e += 8) {
        unsigned int u0 = G2[(size_t)sl[e]     * 64 + lane];
        unsigned int u1 = G2[(size_t)sl[e + 2] * 64 + lane];
        unsigned int u2 = G2[(size_t)sl[e + 4] * 64 + lane];
        unsigned int u3 = G2[(size_t)sl[e + 6] * 64 + lane];
        a0 += bf2f((unsigned short)u0) + bf2f((unsigned short)u1);
        a1 += bf2f((unsigned short)(u0 >> 16)) + bf2f((unsigned short)(u1 >> 16));
        c0 += bf2f((unsigned short)u2) + bf2f((unsigned short)u3);
        c1 += bf2f((unsigned short)(u2 >> 16)) + bf2f((unsigned short)(u3 >> 16));
    }
    for (; e < deg; e += 2) {
        unsigned int u = G2[(size_t)sl[e] * 64 + lane];
        a0 += bf2f((unsigned short)u);
        a1 += bf2f((unsigned short)(u >> 16));
    }
    zsw[w][2 * lane]     = a0 + c0;
    zsw[w][2 * lane + 1] = a1 + c1;
    __syncthreads();

    float dv = rsqrtf((float)deg + 1.0f);
    zs[t] = dv * (zsw[0][t] + zsw[1][t]) + b2[t];
    __syncthreads();

    const int c = t & 63;
    const float* W = (t < 64) ? Wmu : Wlv;
    float s = 0.f;
#pragma unroll 8
    for (int k = 0; k < O_DIM; ++k) s += zs[k] * W[k * C_DIM + c];
    if (t < 64) {
        s += bmu[c];
        mu_out[(size_t)node * C_DIM + c] = s;
        mu_s[c] = s;
    } else {
        s += blv[c];
        lv_out[(size_t)node * C_DIM + c] = s;
        lv_s[c] = s;
    }
    __syncthreads();
    if (t < 64) {
        float stdv = __expf(0.5f * lv_s[c]);
        float v = mu_s[c] + eps[(size_t)node * C_DIM + c] * stdv;
        zr[(size_t)node * C_DIM + c] = (_Float16)v;
    }
}

// ---------------- K5: adj = sigmoid(zr @ zr^T) via fp16 MFMA, nontemporal stores ----------------
__global__ __launch_bounds__(256) void adj_mfma_kernel(
    const _Float16* __restrict__ Z, float* __restrict__ out)
{
    const int tid = threadIdx.x;
    const int lane = tid & 63;
    const int wid = tid >> 6;
    const int r = lane & 15;
    const int kg = lane >> 4;
    const int m0 = blockIdx.y * 128 + (wid >> 1) * 64;
    const int n0 = blockIdx.x * 128 + (wid & 1) * 64;

    f16x8 a[4][2], b[4][2];
#pragma unroll
    for (int mi = 0; mi < 4; ++mi)
#pragma unroll
        for (int ks = 0; ks < 2; ++ks) {
            a[mi][ks] = *(const f16x8*)(Z + (size_t)(m0 + mi * 16 + r) * C_DIM + ks * 32 + kg * 8);
            b[mi][ks] = *(const f16x8*)(Z + (size_t)(n0 + mi * 16 + r) * C_DIM + ks * 32 + kg * 8);
        }

    f32x4 acc[4][4];
#pragma unroll
    for (int mi = 0; mi < 4; ++mi)
#pragma unroll
        for (int ni = 0; ni < 4; ++ni) acc[mi][ni] = (f32x4){0.f, 0.f, 0.f, 0.f};

#pragma unroll
    for (int mi = 0; mi < 4; ++mi)
#pragma unroll
        for (int ni = 0; ni < 4; ++ni) {
            acc[mi][ni] = __builtin_amdgcn_mfma_f32_16x16x32_f16(a[mi][0], b[ni][0], acc[mi][ni], 0, 0, 0);
            acc[mi][ni] = __builtin_amdgcn_mfma_f32_16x16x32_f16(a[mi][1], b[ni][1], acc[mi][ni], 0, 0, 0);
        }

#pragma unroll
    for (int mi = 0; mi < 4; ++mi) {
        int rowb = m0 + mi * 16 + kg * 4;
#pragma unroll
        for (int ni = 0; ni < 4; ++ni) {
            int col = n0 + ni * 16 + r;
#pragma unroll
            for (int i = 0; i < 4; ++i) {
                float v = acc[mi][ni][i];
                float e = __expf(-v);
                float sg = __builtin_amdgcn_rcpf(1.0f + e);
                __builtin_nontemporal_store(sg, &out[(size_t)(rowb + i) * N_NODES + col]);
            }
        }
    }
}

extern "C" void kernel_launch(void* const* d_in, const int* in_sizes, int n_in,
                              void* d_out, int out_size, void* d_ws, size_t ws_size,
                              hipStream_t stream) {
    const float* x   = (const float*)d_in[0];
    const int*   ei  = (const int*)  d_in[1];
    const float* eps = (const float*)d_in[2];
    const float* W1  = (const float*)d_in[3];
    const float* b1  = (const float*)d_in[4];
    const float* W2  = (const float*)d_in[5];
    const float* b2  = (const float*)d_in[6];
    const float* Wmu = (const float*)d_in[7];
    const float* bmu = (const float*)d_in[8];
    const float* Wlv = (const float*)d_in[9];
    const float* blv = (const float*)d_in[10];
    float* out = (float*)d_out;

    const int* srcv = ei;
    const int* dstv = ei + E_EDGES;

    char* p = (char*)d_ws;
    auto carve = [&](size_t bytes) -> void* {
        void* q = (void*)p;
        p += (bytes + 255) & ~(size_t)255;
        return q;
    };
    int* cnt      = (int*)carve(N_NODES * 4);
    int* slots    = (int*)carve((size_t)N_NODES * BCAP * 4);
    unsigned short* w1t  = (unsigned short*)carve((size_t)F_IN * H_DIM * 2);
    unsigned short* w2t  = (unsigned short*)carve((size_t)H_DIM * O_DIM * 2);
    unsigned short* raw1 = (unsigned short*)carve((size_t)N_NODES * H_DIM * 2);
    unsigned short* g2b  = (unsigned short*)carve((size_t)N_NODES * O_DIM * 2);
    _Float16* zr         = (_Float16*)carve((size_t)N_NODES * C_DIM * 2);

    float* mu_out = out + (size_t)N_NODES * N_NODES;
    float* lv_out = mu_out + (size_t)N_NODES * C_DIM;

    // ---- 1. prep: cnt zero + W1^T bf16 + W2^T bf16 (~0.9 MB of work) ----
    {
        const int total = F_IN * H_DIM + H_DIM * O_DIM;  // 163840
        prep_kernel<<<(total + 255) / 256, 256, 0, stream>>>(
            W1, w1t, W2, w2t, cnt);
    }

    // ---- 2. gemm1: edge bucket-fill + raw1 = bf16(x)@w1t^T (x packed in-register) ----
    {
        dim3 grid(H_DIM / 64, N_NODES / 64);   // 4 x 128 = 512 blocks
        gemm1_kernel<<<grid, 256, 0, stream>>>(
            x, w1t, srcv, dstv, cnt, slots, raw1);
    }

    // ---- 3. fused gather1 + gemm2 -> g2b (512 thr / 8 waves per block) ----
    gather_gemm2_kernel<<<N_NODES / 16, 512, 0, stream>>>(
        raw1, cnt, slots, b1, w2t, g2b);

    // ---- 4. fused gather 2 + head (zr fp16) ----
    gather_head_kernel<<<N_NODES, 128, 0, stream>>>(
        g2b, cnt, slots, b2, Wmu, bmu, Wlv, blv, eps,
        mu_out, lv_out, zr);

    // ---- 5. adjacency reconstruction (fp16 MFMA) ----
    {
        dim3 grid(N_NODES / 128, N_NODES / 128);
        adj_mfma_kernel<<<grid, 256, 0, stream>>>(zr, out);
    }
}

// Round 14
// 148.071 us; speedup vs baseline: 1.4168x; 1.1231x over previous
//
#include <hip/hip_runtime.h>
#include <hip/hip_bf16.h>

#define N_NODES 8192
#define F_IN    512
#define H_DIM   256
#define O_DIM   128
#define C_DIM   64
#define E_EDGES 262144
#define BCAP    96

typedef __attribute__((ext_vector_type(8))) short bf16x8;
typedef __attribute__((ext_vector_type(8))) _Float16 f16x8;
typedef __attribute__((ext_vector_type(4))) float f32x4;

__device__ inline unsigned short f2bf(float v) {
    __hip_bfloat16 h = __float2bfloat16(v);
    return *reinterpret_cast<unsigned short*>(&h);
}
__device__ inline float bf2f(unsigned short u) {
    return __uint_as_float((unsigned)u << 16);
}
__device__ inline float4 bf4_to_f4(ushort4 u) {
    float4 f;
    f.x = bf2f(u.x); f.y = bf2f(u.y); f.z = bf2f(u.z); f.w = bf2f(u.w);
    return f;
}
__device__ inline bf16x8 pack_bf8(float4 a, float4 b) {
    bf16x8 r;
    r[0] = (short)f2bf(a.x); r[1] = (short)f2bf(a.y);
    r[2] = (short)f2bf(a.z); r[3] = (short)f2bf(a.w);
    r[4] = (short)f2bf(b.x); r[5] = (short)f2bf(b.y);
    r[6] = (short)f2bf(b.z); r[7] = (short)f2bf(b.w);
    return r;
}

// ---------------- K1: prep — zero cnt; W1 -> W1^T bf16; W2 -> W2^T bf16 ----------------
__global__ __launch_bounds__(256) void prep_kernel(
    const float* __restrict__ W1, unsigned short* __restrict__ w1t,
    const float* __restrict__ W2, unsigned short* __restrict__ w2t,
    int* __restrict__ cnt)
{
    const int NW1 = F_IN * H_DIM;             // 131072
    const int NW2 = H_DIM * O_DIM;            // 32768
    int idx = blockIdx.x * 256 + threadIdx.x;
    if (idx < N_NODES) cnt[idx] = 0;
    if (idx < NW1) {
        int k = idx / H_DIM, n = idx % H_DIM;
        w1t[n * F_IN + k] = f2bf(W1[idx]);
    } else if (idx < NW1 + NW2) {
        int j = idx - NW1;
        int k = j / O_DIM, n = j % O_DIM;
        w2t[n * H_DIM + k] = f2bf(W2[j]);
    }
}

// ---------------- K2: gemm1 — edge bucket-fill + raw1 = bf16(bf16(x) @ w1t^T) ----------------
__global__ __launch_bounds__(256) void gemm1_kernel(
    const float* __restrict__ x,
    const unsigned short* __restrict__ Bt,
    const int* __restrict__ srcv, const int* __restrict__ dstv,
    int* __restrict__ cnt, int* __restrict__ slots,
    unsigned short* __restrict__ out)   // raw1 [N_NODES][H_DIM]
{
    // edge fill: exactly 2 edges per thread (512 blocks * 256 thr * 2 = 262144)
    {
        int flat = (blockIdx.y * gridDim.x + blockIdx.x) * 256 + threadIdx.x;
        int e0 = flat * 2;
#pragma unroll
        for (int j = 0; j < 2; ++j) {
            int d = dstv[e0 + j];
            int pos = atomicAdd(&cnt[d], 1);
            slots[d * BCAP + pos] = srcv[e0 + j];
        }
    }

    constexpr int N = H_DIM, K = F_IN, MW = 2, NW = 2;
    const int tid = threadIdx.x;
    const int lane = tid & 63;
    const int wid = tid >> 6;
    const int r = lane & 15;
    const int kg = lane >> 4;
    const int m0 = blockIdx.y * (2 * MW * 16) + (wid >> 1) * (MW * 16);
    const int n0 = blockIdx.x * (2 * NW * 16) + (wid & 1) * (NW * 16);

    f32x4 acc[MW][NW];
#pragma unroll
    for (int mi = 0; mi < MW; ++mi)
#pragma unroll
        for (int ni = 0; ni < NW; ++ni) acc[mi][ni] = (f32x4){0.f, 0.f, 0.f, 0.f};

    for (int k0 = 0; k0 < K; k0 += 32) {
        const int kof = k0 + kg * 8;
        bf16x8 a[MW], b[NW];
#pragma unroll
        for (int mi = 0; mi < MW; ++mi) {
            const float* xr = x + (size_t)(m0 + mi * 16 + r) * K + kof;
            float4 f0 = *(const float4*)xr;
            float4 f1 = *(const float4*)(xr + 4);
            a[mi] = pack_bf8(f0, f1);
        }
#pragma unroll
        for (int ni = 0; ni < NW; ++ni)
            b[ni] = *(const bf16x8*)(Bt + (size_t)(n0 + ni * 16 + r) * K + kof);
#pragma unroll
        for (int mi = 0; mi < MW; ++mi)
#pragma unroll
            for (int ni = 0; ni < NW; ++ni)
                acc[mi][ni] = __builtin_amdgcn_mfma_f32_16x16x32_bf16(a[mi], b[ni], acc[mi][ni], 0, 0, 0);
    }

#pragma unroll
    for (int mi = 0; mi < MW; ++mi) {
        int rowb = m0 + mi * 16 + kg * 4;
#pragma unroll
        for (int ni = 0; ni < NW; ++ni) {
            int col = n0 + ni * 16 + r;
#pragma unroll
            for (int i = 0; i < 4; ++i)
                out[(size_t)(rowb + i) * N + col] = f2bf(acc[mi][ni][i]);
        }
    }
}

// ---------------- K3: fused gather1 + gemm2 (512 threads, 8 waves) ----------------
__global__ __launch_bounds__(512) void gather_gemm2_kernel(
    const unsigned short* __restrict__ raw,   // raw1 [8192][256] bf16, unscaled
    const int* __restrict__ cnt, const int* __restrict__ slots,
    const float* __restrict__ b1,
    const unsigned short* __restrict__ w2t,
    unsigned short* __restrict__ g2b)         // [8192][128] bf16, dinv-scaled
{
    __shared__ unsigned short hs[16 * 256];   // 8 KB, row stride 512 B, XOR-swizzled 16B slots
    const int tid = threadIdx.x;
    const int wid = tid >> 6;                 // 0..7
    const int lane = tid & 63;
    const int nb = blockIdx.x * 16;
    const ushort4* G4 = (const ushort4*)raw;

    // ---- phase 1: each wave gathers 2 node rows ----
    for (int q = 0; q < 2; ++q) {
        const int ln = wid * 2 + q;
        const int node = nb + ln;
        const int deg = cnt[node];
        const int* sl = slots + node * BCAP;
        const float di = rsqrtf((float)deg + 1.0f);

        float4 selfv = bf4_to_f4(G4[(size_t)node * 64 + lane]);
        float4 acc, acc2;
        acc.x = di * selfv.x; acc.y = di * selfv.y;
        acc.z = di * selfv.z; acc.w = di * selfv.w;
        acc2 = make_float4(0.f, 0.f, 0.f, 0.f);

        int e = 0;
        for (; e + 8 <= deg; e += 8) {
            int s[8];
            ushort4 u[8];
            float d[8];
#pragma unroll
            for (int j = 0; j < 8; ++j) s[j] = sl[e + j];
#pragma unroll
            for (int j = 0; j < 8; ++j) u[j] = G4[(size_t)s[j] * 64 + lane];
#pragma unroll
            for (int j = 0; j < 8; ++j) d[j] = rsqrtf((float)cnt[s[j]] + 1.0f);
#pragma unroll
            for (int j = 0; j < 8; j += 2) {
                float4 v0 = bf4_to_f4(u[j]);
                float4 v1 = bf4_to_f4(u[j + 1]);
                acc.x = fmaf(d[j], v0.x, acc.x);     acc.y = fmaf(d[j], v0.y, acc.y);
                acc.z = fmaf(d[j], v0.z, acc.z);     acc.w = fmaf(d[j], v0.w, acc.w);
                acc2.x = fmaf(d[j+1], v1.x, acc2.x); acc2.y = fmaf(d[j+1], v1.y, acc2.y);
                acc2.z = fmaf(d[j+1], v1.z, acc2.z); acc2.w = fmaf(d[j+1], v1.w, acc2.w);
            }
        }
        for (; e < deg; ++e) {
            int s0 = sl[e];
            float d0 = rsqrtf((float)cnt[s0] + 1.0f);
            float4 v0 = bf4_to_f4(G4[(size_t)s0 * 64 + lane]);
            acc.x = fmaf(d0, v0.x, acc.x); acc.y = fmaf(d0, v0.y, acc.y);
            acc.z = fmaf(d0, v0.z, acc.z); acc.w = fmaf(d0, v0.w, acc.w);
        }
        acc.x += acc2.x; acc.y += acc2.y; acc.z += acc2.z; acc.w += acc2.w;

        const float4 bv = ((const float4*)b1)[lane];
        float4 rr;
        rr.x = di * acc.x + bv.x;
        rr.y = di * acc.y + bv.y;
        rr.z = di * acc.z + bv.z;
        rr.w = di * acc.w + bv.w;
        rr.x = rr.x > 0.f ? rr.x : 0.f;
        rr.y = rr.y > 0.f ? rr.y : 0.f;
        rr.z = rr.z > 0.f ? rr.z : 0.f;
        rr.w = rr.w > 0.f ? rr.w : 0.f;

        ushort4 hv;
        hv.x = f2bf(rr.x); hv.y = f2bf(rr.y); hv.z = f2bf(rr.z); hv.w = f2bf(rr.w);
        int s0 = (lane >> 1) ^ (ln & 7);
        *(ushort4*)((char*)hs + ln * 512 + (s0 << 4) + (lane & 1) * 8) = hv;
    }
    __syncthreads();

    // ---- phase 2: 16x256 @ W2^T(128x256) -> 16x128; wave wid covers cols wid*16..+15 ----
    const int r = lane & 15;
    const int kg = lane >> 4;
    const int wn = wid * 16;

    f32x4 acc = (f32x4){0.f, 0.f, 0.f, 0.f};
    for (int k0 = 0; k0 < H_DIM; k0 += 32) {
        int slot = ((k0 >> 3) + kg) ^ (r & 7);
        bf16x8 a = *(const bf16x8*)((const char*)hs + r * 512 + (slot << 4));
        bf16x8 b = *(const bf16x8*)(w2t + (size_t)(wn + r) * H_DIM + k0 + kg * 8);
        acc = __builtin_amdgcn_mfma_f32_16x16x32_bf16(a, b, acc, 0, 0, 0);
    }

#pragma unroll
    for (int i = 0; i < 4; ++i) {
        int row = nb + kg * 4 + i;
        float di = rsqrtf((float)cnt[row] + 1.0f);
        g2b[(size_t)row * O_DIM + wn + r] = f2bf(di * acc[i]);
    }
}

// ---------------- K4: fused gather layer 2 + head (ushort2 loads, 2-wave split) ----------------
__global__ __launch_bounds__(128) void gather_head_kernel(
    const unsigned short* __restrict__ g2,   // [8192][128] bf16, dinv-scaled
    const int* __restrict__ cnt, const int* __restrict__ slots,
    const float* __restrict__ b2,
    const float* __restrict__ Wmu, const float* __restrict__ bmu,
    const float* __restrict__ Wlv, const float* __restrict__ blv,
    const float* __restrict__ eps,
    float* __restrict__ mu_out, float* __restrict__ lv_out,
    _Float16* __restrict__ zr)
{
    __shared__ float zsw[2][O_DIM];
    __shared__ float zs[O_DIM];
    __shared__ float mu_s[C_DIM];
    __shared__ float lv_s[C_DIM];
    const int node = blockIdx.x;
    const int t = threadIdx.x;
    const int w = t >> 6;
    const int lane = t & 63;

    const int deg = cnt[node];
    const int* sl = slots + node * BCAP;
    const unsigned int* G2 = (const unsigned int*)g2;  // row stride 64 uints (128 bf16)

    float a0 = 0.f, a1 = 0.f, c0 = 0.f, c1 = 0.f;
    if (w == 0) {
        unsigned int u = G2[(size_t)node * 64 + lane];
        a0 = bf2f((unsigned short)u);
        a1 = bf2f((unsigned short)(u >> 16));
    }
    int e = w;
    for (; e + 6 < deg; e += 8) {
        unsigned int u0 = G2[(size_t)sl[e]     * 64 + lane];
        unsigned int u1 = G2[(size_t)sl[e + 2] * 64 + lane];
        unsigned int u2 = G2[(size_t)sl[e + 4] * 64 + lane];
        unsigned int u3 = G2[(size_t)sl[e + 6] * 64 + lane];
        a0 += bf2f((unsigned short)u0) + bf2f((unsigned short)u1);
        a1 += bf2f((unsigned short)(u0 >> 16)) + bf2f((unsigned short)(u1 >> 16));
        c0 += bf2f((unsigned short)u2) + bf2f((unsigned short)u3);
        c1 += bf2f((unsigned short)(u2 >> 16)) + bf2f((unsigned short)(u3 >> 16));
    }
    for (; e < deg; e += 2) {
        unsigned int u = G2[(size_t)sl[e] * 64 + lane];
        a0 += bf2f((unsigned short)u);
        a1 += bf2f((unsigned short)(u >> 16));
    }
    zsw[w][2 * lane]     = a0 + c0;
    zsw[w][2 * lane + 1] = a1 + c1;
    __syncthreads();

    float dv = rsqrtf((float)deg + 1.0f);
    zs[t] = dv * (zsw[0][t] + zsw[1][t]) + b2[t];
    __syncthreads();

    const int c = t & 63;
    const float* W = (t < 64) ? Wmu : Wlv;
    float s = 0.f;
#pragma unroll 8
    for (int k = 0; k < O_DIM; ++k) s += zs[k] * W[k * C_DIM + c];
    if (t < 64) {
        s += bmu[c];
        mu_out[(size_t)node * C_DIM + c] = s;
        mu_s[c] = s;
    } else {
        s += blv[c];
        lv_out[(size_t)node * C_DIM + c] = s;
        lv_s[c] = s;
    }
    __syncthreads();
    if (t < 64) {
        float stdv = __expf(0.5f * lv_s[c]);
        float v = mu_s[c] + eps[(size_t)node * C_DIM + c] * stdv;
        zr[(size_t)node * C_DIM + c] = (_Float16)v;
    }
}

// ---------------- K5: adj = sigmoid(zr @ zr^T), fp16 MFMA, LDS-staged coalesced NT stores ----------------
__global__ __launch_bounds__(256) void adj_mfma_kernel(
    const _Float16* __restrict__ Z, float* __restrict__ out)
{
    __shared__ float ls[128 * 128];   // 64 KB; float4-slot XOR-swizzled by row&7
    const int tid = threadIdx.x;
    const int lane = tid & 63;
    const int wid = tid >> 6;
    const int r = lane & 15;
    const int kg = lane >> 4;
    const int mb = blockIdx.y * 128;
    const int nb = blockIdx.x * 128;
    const int m0 = (wid >> 1) * 64;   // local row base of this wave
    const int n0 = (wid & 1) * 64;    // local col base

    f16x8 a[4][2], b[4][2];
#pragma unroll
    for (int mi = 0; mi < 4; ++mi)
#pragma unroll
        for (int ks = 0; ks < 2; ++ks) {
            a[mi][ks] = *(const f16x8*)(Z + (size_t)(mb + m0 + mi * 16 + r) * C_DIM + ks * 32 + kg * 8);
            b[mi][ks] = *(const f16x8*)(Z + (size_t)(nb + n0 + mi * 16 + r) * C_DIM + ks * 32 + kg * 8);
        }

    f32x4 acc[4][4];
#pragma unroll
    for (int mi = 0; mi < 4; ++mi)
#pragma unroll
        for (int ni = 0; ni < 4; ++ni) acc[mi][ni] = (f32x4){0.f, 0.f, 0.f, 0.f};

#pragma unroll
    for (int mi = 0; mi < 4; ++mi)
#pragma unroll
        for (int ni = 0; ni < 4; ++ni) {
            acc[mi][ni] = __builtin_amdgcn_mfma_f32_16x16x32_f16(a[mi][0], b[ni][0], acc[mi][ni], 0, 0, 0);
            acc[mi][ni] = __builtin_amdgcn_mfma_f32_16x16x32_f16(a[mi][1], b[ni][1], acc[mi][ni], 0, 0, 0);
        }

    // sigmoid -> LDS (swizzled float4 slots: slot = (lc>>2) ^ (lr&7), scalar lane offset lc&3)
#pragma unroll
    for (int mi = 0; mi < 4; ++mi) {
        int lr_b = m0 + mi * 16 + kg * 4;
#pragma unroll
        for (int ni = 0; ni < 4; ++ni) {
            int lc = n0 + ni * 16 + r;
#pragma unroll
            for (int i = 0; i < 4; ++i) {
                float v = acc[mi][ni][i];
                float e = __expf(-v);
                float sg = __builtin_amdgcn_rcpf(1.0f + e);
                int lr = lr_b + i;
                ls[lr * 128 + (((lc >> 2) ^ (lr & 7)) << 2) + (lc & 3)] = sg;
            }
        }
    }
    __syncthreads();

    // coalesced NT stores: 4096 float4 / 256 thr = 16 per thread; 512B contiguous per wave-instr
#pragma unroll
    for (int j = 0; j < 16; ++j) {
        int idx = j * 256 + tid;
        int row = idx >> 5;        // 32 float4 per 128-col row
        int s = idx & 31;
        f32x4 v = *(const f32x4*)&ls[row * 128 + (((s ^ (row & 7)) & 31) << 2)];
        __builtin_nontemporal_store(v, (f32x4*)&out[(size_t)(mb + row) * N_NODES + nb + s * 4]);
    }
}

extern "C" void kernel_launch(void* const* d_in, const int* in_sizes, int n_in,
                              void* d_out, int out_size, void* d_ws, size_t ws_size,
                              hipStream_t stream) {
    const float* x   = (const float*)d_in[0];
    const int*   ei  = (const int*)  d_in[1];
    const float* eps = (const float*)d_in[2];
    const float* W1  = (const float*)d_in[3];
    const float* b1  = (const float*)d_in[4];
    const float* W2  = (const float*)d_in[5];
    const float* b2  = (const float*)d_in[6];
    const float* Wmu = (const float*)d_in[7];
    const float* bmu = (const float*)d_in[8];
    const float* Wlv = (const float*)d_in[9];
    const float* blv = (const float*)d_in[10];
    float* out = (float*)d_out;

    const int* srcv = ei;
    const int* dstv = ei + E_EDGES;

    char* p = (char*)d_ws;
    auto carve = [&](size_t bytes) -> void* {
        void* q = (void*)p;
        p += (bytes + 255) & ~(size_t)255;
        return q;
    };
    int* cnt      = (int*)carve(N_NODES * 4);
    int* slots    = (int*)carve((size_t)N_NODES * BCAP * 4);
    unsigned short* w1t  = (unsigned short*)carve((size_t)F_IN * H_DIM * 2);
    unsigned short* w2t  = (unsigned short*)carve((size_t)H_DIM * O_DIM * 2);
    unsigned short* raw1 = (unsigned short*)carve((size_t)N_NODES * H_DIM * 2);
    unsigned short* g2b  = (unsigned short*)carve((size_t)N_NODES * O_DIM * 2);
    _Float16* zr         = (_Float16*)carve((size_t)N_NODES * C_DIM * 2);

    float* mu_out = out + (size_t)N_NODES * N_NODES;
    float* lv_out = mu_out + (size_t)N_NODES * C_DIM;

    // ---- 1. prep: cnt zero + W1^T bf16 + W2^T bf16 ----
    {
        const int total = F_IN * H_DIM + H_DIM * O_DIM;  // 163840
        prep_kernel<<<(total + 255) / 256, 256, 0, stream>>>(
            W1, w1t, W2, w2t, cnt);
    }

    // ---- 2. gemm1: edge bucket-fill + raw1 = bf16(x)@w1t^T ----
    {
        dim3 grid(H_DIM / 64, N_NODES / 64);   // 4 x 128 = 512 blocks
        gemm1_kernel<<<grid, 256, 0, stream>>>(
            x, w1t, srcv, dstv, cnt, slots, raw1);
    }

    // ---- 3. fused gather1 + gemm2 -> g2b ----
    gather_gemm2_kernel<<<N_NODES / 16, 512, 0, stream>>>(
        raw1, cnt, slots, b1, w2t, g2b);

    // ---- 4. fused gather 2 + head (zr fp16) ----
    gather_head_kernel<<<N_NODES, 128, 0, stream>>>(
        g2b, cnt, slots, b2, Wmu, bmu, Wlv, blv, eps,
        mu_out, lv_out, zr);

    // ---- 5. adjacency reconstruction (LDS-staged coalesced NT stores) ----
    {
        dim3 grid(N_NODES / 128, N_NODES / 128);
        adj_mfma_kernel<<<grid, 256, 0, stream>>>(zr, out);
    }
}